// Round 12
// baseline (312.850 us; speedup 1.0000x reference)
//
#include <hip/hip_runtime.h>
#include <math.h>

namespace {

constexpr int NROWS = 2048;   // B*T
constexpr int DIN   = 512;
constexpr int DOUT  = 512;
constexpr int HEADS = 4;
constexpr int KDIM  = 512;
constexpr int HALFD = 256;
constexpr int NKEYS = 512;
constexpr int KNN   = 32;

typedef short bf16x8 __attribute__((ext_vector_type(8)));
typedef float f32x4  __attribute__((ext_vector_type(4)));

__device__ inline unsigned short f2bf(float f) {   // round-to-nearest-even
    unsigned u = __float_as_uint(f);
    unsigned r = u + 0x7FFFu + ((u >> 16) & 1u);
    return (unsigned short)(r >> 16);
}
__device__ inline float bf2f(unsigned short h) {
    return __uint_as_float((unsigned)h << 16);
}
__device__ inline unsigned fmap(float f) {
    unsigned u = __float_as_uint(f);
    return (u & 0x80000000u) ? ~u : (u | 0x80000000u);
}
__device__ inline float funmap(unsigned m) {
    unsigned u = (m & 0x80000000u) ? (m & 0x7FFFFFFFu) : ~m;
    return __uint_as_float(u);
}
__device__ inline unsigned long long shflxor64(unsigned long long x, int m) {
    unsigned lo = (unsigned)x, hi = (unsigned)(x >> 32);
    lo = __shfl_xor(lo, m);
    hi = __shfl_xor(hi, m);
    return ((unsigned long long)hi << 32) | lo;
}
// full 64-lane bitonic sort, descending by u64 key; lane l ends with rank-l
__device__ inline unsigned long long bitonic64_desc(unsigned long long v, int lane) {
    #pragma unroll
    for (int k = 2; k <= 64; k <<= 1) {
        #pragma unroll
        for (int j = k >> 1; j > 0; j >>= 1) {
            const unsigned long long o = shflxor64(v, j);
            const bool keepMax = (((lane & j) == 0) == ((lane & k) == 0));
            const bool oGreater = o > v;
            v = (keepMax == oGreater) ? o : v;
        }
    }
    return v;
}

// ====== splits: x 3-way (z0), Wsw 2-way (z1), keys 3-way (z2),
//                Wv 2-way (z3), Wq 3-way (z4)
__global__ __launch_bounds__(256)
void split6(const float* __restrict__ x, const float* __restrict__ wsw,
            const float* __restrict__ keys, const float* __restrict__ wv,
            const float* __restrict__ wq,
            unsigned short* __restrict__ xh, unsigned short* __restrict__ xm,
            unsigned short* __restrict__ xl,
            unsigned short* __restrict__ wh, unsigned short* __restrict__ wm,
            unsigned short* __restrict__ kh, unsigned short* __restrict__ km,
            unsigned short* __restrict__ kl,
            unsigned short* __restrict__ vh, unsigned short* __restrict__ vm,
            unsigned short* __restrict__ qwh, unsigned short* __restrict__ qwm,
            unsigned short* __restrict__ qwl)
{
    const int z = blockIdx.z;
    const int i = (blockIdx.x * 256 + threadIdx.x) * 4;
    const bool three = (z == 0) || (z == 2) || (z == 4);
    const float* src = (z == 0) ? x : (z == 1) ? wsw : (z == 2) ? keys
                     : (z == 3) ? wv : wq;
    unsigned short* ph = (z == 0) ? xh : (z == 1) ? wh : (z == 2) ? kh
                       : (z == 3) ? vh : qwh;
    unsigned short* pm = (z == 0) ? xm : (z == 1) ? wm : (z == 2) ? km
                       : (z == 3) ? vm : qwm;
    unsigned short* pl = (z == 0) ? xl : (z == 2) ? kl : qwl;
    const int n = (z == 1 || z == 3) ? 262144 : 1048576;
    if (i >= n) return;
    const float4 v = *(const float4*)(src + i);
    ushort4 oh, om, ol;
    float r;
    oh.x = f2bf(v.x); r = v.x - bf2f(oh.x); om.x = f2bf(r); ol.x = f2bf(r - bf2f(om.x));
    oh.y = f2bf(v.y); r = v.y - bf2f(oh.y); om.y = f2bf(r); ol.y = f2bf(r - bf2f(om.y));
    oh.z = f2bf(v.z); r = v.z - bf2f(oh.z); om.z = f2bf(r); ol.z = f2bf(r - bf2f(om.z));
    oh.w = f2bf(v.w); r = v.w - bf2f(oh.w); om.w = f2bf(r); ol.w = f2bf(r - bf2f(om.w));
    *(ushort4*)(ph + i) = oh;
    *(ushort4*)(pm + i) = om;
    if (three) *(ushort4*)(pl + i) = ol;
}

// ===== q = x @ Wq^T + bq via 6-term triple-split MFMA, 128x64 tile =========
// Output split 3-way bf16 (qh/qm/ql).  Grid (16,32) = 512 blocks.
__global__ __launch_bounds__(256)
void mfma_q(const unsigned short* __restrict__ xh, const unsigned short* __restrict__ xm,
            const unsigned short* __restrict__ xl,
            const unsigned short* __restrict__ WH, const unsigned short* __restrict__ WM,
            const unsigned short* __restrict__ WL,
            const float* __restrict__ bias,
            unsigned short* __restrict__ qh, unsigned short* __restrict__ qm,
            unsigned short* __restrict__ ql)
{
    __shared__ __align__(16) unsigned short Al[128 * 64];
    __shared__ __align__(16) unsigned short Bl[64 * 64];
    const int tid = threadIdx.x;
    const int wid = tid >> 6, lane = tid & 63;
    const int r16 = lane & 15, kc = lane >> 4;
    const int wr = wid >> 1, wc = wid & 1;
    const int m0 = blockIdx.x * 128, n0 = blockIdx.y * 64;
    const int srowA = tid >> 1;          // 0..127
    const int skbA  = (tid & 1) << 5;    // 0/32
    const int srowB = tid >> 2;          // 0..63
    const int skbB  = (tid & 3) << 4;    // 0,16,32,48
    constexpr int TA[6] = {0, 0, 1, 0, 2, 1};
    constexpr int TB[6] = {0, 1, 0, 2, 0, 1};
    const unsigned short* As[3] = {xh, xm, xl};
    const unsigned short* Bs[3] = {WH, WM, WL};

    f32x4 acc[4][2] = {};
    for (int term = 0; term < 6; ++term) {
        const unsigned short* Ag = As[TA[term]] + (size_t)(m0 + srowA) * DIN + skbA;
        const unsigned short* Bg = Bs[TB[term]] + (size_t)(n0 + srowB) * DIN + skbB;
        for (int k0 = 0; k0 < DIN; k0 += 64) {
            __syncthreads();
            #pragma unroll
            for (int j = 0; j < 4; ++j) {
                const uint4 va = *(const uint4*)(Ag + k0 + j * 8);
                const unsigned ba = (unsigned)(srowA * 128 + (skbA + j * 8) * 2)
                                  ^ ((srowA & 7) << 4);
                *(uint4*)((char*)Al + ba) = va;
            }
            #pragma unroll
            for (int j = 0; j < 2; ++j) {
                const uint4 vb = *(const uint4*)(Bg + k0 + j * 8);
                const unsigned bb = (unsigned)(srowB * 128 + (skbB + j * 8) * 2)
                                  ^ ((srowB & 7) << 4);
                *(uint4*)((char*)Bl + bb) = vb;
            }
            __syncthreads();
            #pragma unroll
            for (int ks = 0; ks < 2; ++ks) {
                bf16x8 af[4], bfr[2];
                #pragma unroll
                for (int f = 0; f < 4; ++f) {
                    const int am = wr * 64 + f * 16 + r16;
                    af[f] = *(const bf16x8*)((const char*)Al +
                        ((unsigned)(am * 128 + ks * 64 + kc * 16) ^ ((am & 7) << 4)));
                }
                #pragma unroll
                for (int f = 0; f < 2; ++f) {
                    const int bn = wc * 32 + f * 16 + r16;
                    bfr[f] = *(const bf16x8*)((const char*)Bl +
                        ((unsigned)(bn * 128 + ks * 64 + kc * 16) ^ ((bn & 7) << 4)));
                }
                #pragma unroll
                for (int fm = 0; fm < 4; ++fm)
                    #pragma unroll
                    for (int fn = 0; fn < 2; ++fn)
                        acc[fm][fn] = __builtin_amdgcn_mfma_f32_16x16x32_bf16(
                            af[fm], bfr[fn], acc[fm][fn], 0, 0, 0);
            }
        }
    }

    #pragma unroll
    for (int fm = 0; fm < 4; ++fm) {
        const int row = m0 + wr * 64 + fm * 16 + kc * 4;
        #pragma unroll
        for (int fn = 0; fn < 2; ++fn) {
            const int col = n0 + wc * 32 + fn * 16 + r16;
            const float b = bias[col];
            #pragma unroll
            for (int r = 0; r < 4; ++r) {
                const float o = acc[fm][fn][r] + b;
                const unsigned short h = f2bf(o);
                const float rr = o - bf2f(h);
                const unsigned short m = f2bf(rr);
                const unsigned short l = f2bf(rr - bf2f(m));
                const size_t off = (size_t)(row + r) * (HEADS * KDIM) + col;
                qh[off] = h; qm[off] = m; ql[off] = l;
            }
        }
    }
}

// ============ LDS-staged bf16 MFMA: scores (z<8, 6-term triple-split) ======
// z==8: gate = silu(3-term) (R8/R11-proven: 128x128, BK=64, T2 swizzle)
__global__ __launch_bounds__(256)
void mfma_sg(const unsigned short* __restrict__ qh, const unsigned short* __restrict__ qm,
             const unsigned short* __restrict__ ql,
             const unsigned short* __restrict__ kh, const unsigned short* __restrict__ km,
             const unsigned short* __restrict__ kl,
             const unsigned short* __restrict__ xh, const unsigned short* __restrict__ xm,
             const unsigned short* __restrict__ wh, const unsigned short* __restrict__ wm,
             const float* __restrict__ bsw,
             float* __restrict__ s, float* __restrict__ gate)
{
    __shared__ __align__(16) unsigned short Al[128 * 64];
    __shared__ __align__(16) unsigned short Bl[128 * 64];
    const int tid  = threadIdx.x;
    const int wid  = tid >> 6, lane = tid & 63;
    const int r16  = lane & 15, kc = lane >> 4;
    const int wr   = wid >> 1, wc = wid & 1;
    const int z    = blockIdx.z;
    const int bx   = blockIdx.x, by = blockIdx.y;
    const int srow = tid >> 1;
    const int skb  = (tid & 1) << 5;
    const unsigned swzw = (unsigned)((srow & 7) << 4);

    constexpr int TA[6] = {0, 0, 1, 0, 2, 1};
    constexpr int TB[6] = {0, 1, 0, 2, 0, 1};
    const unsigned short* As[3];
    const unsigned short* Bs[3];
    int K, nterm;
    size_t aoff, boff;
    if (z < 8) {
        As[0] = qh; As[1] = qm; As[2] = ql;
        Bs[0] = kh; Bs[1] = km; Bs[2] = kl;
        K = HALFD; nterm = 6;
        aoff = (size_t)(bx * 128 + srow) * (HEADS * KDIM)
             + (z >> 1) * KDIM + (z & 1) * HALFD + skb;
        boff = ((size_t)z * NKEYS + by * 128 + srow) * HALFD + skb;
    } else {
        As[0] = xh; As[1] = xm; As[2] = nullptr;
        Bs[0] = wh; Bs[1] = wm; Bs[2] = nullptr;
        K = DIN; nterm = 3;
        aoff = (size_t)(bx * 128 + srow) * DIN + skb;
        boff = (size_t)(by * 128 + srow) * DIN + skb;
    }

    f32x4 acc[4][4] = {};
    for (int term = 0; term < nterm; ++term) {
        const unsigned short* Ag = As[TA[term]] + aoff;
        const unsigned short* Bg = Bs[TB[term]] + boff;
        for (int k0 = 0; k0 < K; k0 += 64) {
            __syncthreads();
            #pragma unroll
            for (int j = 0; j < 4; ++j) {
                const uint4 va = *(const uint4*)(Ag + k0 + j * 8);
                const uint4 vb = *(const uint4*)(Bg + k0 + j * 8);
                const unsigned boff2 = (unsigned)(srow * 128 + (skb + j * 8) * 2) ^ swzw;
                *(uint4*)((char*)Al + boff2) = va;
                *(uint4*)((char*)Bl + boff2) = vb;
            }
            __syncthreads();
            #pragma unroll
            for (int ks = 0; ks < 2; ++ks) {
                bf16x8 af[4], bf[4];
                #pragma unroll
                for (int f = 0; f < 4; ++f) {
                    const int am = wr * 64 + f * 16 + r16;
                    af[f] = *(const bf16x8*)((const char*)Al +
                        ((unsigned)(am * 128 + ks * 64 + kc * 16) ^ ((am & 7) << 4)));
                    const int bn = wc * 64 + f * 16 + r16;
                    bf[f] = *(const bf16x8*)((const char*)Bl +
                        ((unsigned)(bn * 128 + ks * 64 + kc * 16) ^ ((bn & 7) << 4)));
                }
                #pragma unroll
                for (int fm = 0; fm < 4; ++fm)
                    #pragma unroll
                    for (int fn = 0; fn < 4; ++fn)
                        acc[fm][fn] = __builtin_amdgcn_mfma_f32_16x16x32_bf16(
                            af[fm], bf[fn], acc[fm][fn], 0, 0, 0);
            }
        }
    }

    #pragma unroll
    for (int fm = 0; fm < 4; ++fm) {
        const int row = bx * 128 + wr * 64 + fm * 16 + kc * 4;
        #pragma unroll
        for (int fn = 0; fn < 4; ++fn) {
            const int col = by * 128 + wc * 64 + fn * 16 + r16;
            #pragma unroll
            for (int r = 0; r < 4; ++r) {
                float v = acc[fm][fn][r];
                if (z < 8) {
                    s[(size_t)(row + r) * (HEADS * 2 * NKEYS) + z * NKEYS + col] = v;
                } else {
                    v += bsw[col];
                    v = v / (1.f + expf(-v));
                    gate[(size_t)(row + r) * DOUT + col] = v;
                }
            }
        }
    }
}

// ====== topk4 (R11-proven): tau-select [32,64] -> bitonic top-32 -> stage 2
__global__ __launch_bounds__(64)
void topk4(const float* __restrict__ s,
           float* __restrict__ w_out, int* __restrict__ idx_out)
{
    const int nh   = blockIdx.x;
    const int lane = threadIdx.x;
    const int sub  = lane >> 5;
    const int sl   = lane & 31;
    __shared__ unsigned long long pkl[2][64];
    __shared__ float ts[2][KNN];
    __shared__ int   ti[2][KNN];

    const float* sb = s + (size_t)nh * (2 * NKEYS) + sub * NKEYS;
    unsigned u[16];
    #pragma unroll
    for (int i = 0; i < 16; ++i) u[i] = fmap(sb[i * 32 + sl]);

    unsigned lo = 0, hi = 0xFFFFFFFFu, tau = 0;
    bool found = false;
    for (int iter = 0; iter < 30; ++iter) {
        if (__all(found)) break;
        const unsigned mid = lo + ((hi - lo) >> 1);
        int c = 0;
        #pragma unroll
        for (int i = 0; i < 16; ++i) c += (u[i] >= mid) ? 1 : 0;
        #pragma unroll
        for (int off = 1; off <= 16; off <<= 1) c += __shfl_xor(c, off);
        if (!found) {
            if (c >= 32 && c <= 64) { tau = mid; found = true; }
            else if (c > 64) lo = mid + 1;
            else hi = mid - 1;
        }
    }
    if (!found) tau = lo;

    pkl[0][lane] = 0ull;
    pkl[1][lane] = 0ull;
    __syncthreads();
    unsigned msk = 0;
    #pragma unroll
    for (int i = 0; i < 16; ++i) msk |= (u[i] >= tau ? 1u : 0u) << i;
    int mc = __popc(msk);
    int pfx = mc;
    #pragma unroll
    for (int d = 1; d <= 16; d <<= 1) {
        const int t = __shfl_up(pfx, d);
        if (sl >= d) pfx += t;
    }
    int slot = pfx - mc;
    #pragma unroll
    for (int i = 0; i < 16; ++i)
        if ((msk >> i) & 1u) {
            if (slot < 64)
                pkl[sub][slot] = ((unsigned long long)u[i] << 32)
                               | (unsigned)(~((i << 5) | sl));
            ++slot;
        }
    __syncthreads();

    #pragma unroll
    for (int p = 0; p < 2; ++p) {
        unsigned long long v = bitonic64_desc(pkl[p][lane], lane);
        if (lane < KNN) {
            ts[p][lane] = funmap((unsigned)(v >> 32));
            ti[p][lane] = (int)(~(unsigned)v) & (NKEYS - 1);
        }
    }
    __syncthreads();

    float cv[2]; int cc[2];
    #pragma unroll
    for (int t = 0; t < 2; ++t) {
        const int c = t * 64 + lane;
        int ii = -1, jj = 0, off = 0;
        #pragma unroll
        for (int i = 0; i < 32; ++i) {
            const int cnt = 32 / (i + 1);
            const bool in = (c >= off) && (c < off + cnt);
            ii = in ? i : ii;
            jj = in ? c - off : jj;
            off += cnt;
        }
        if (ii >= 0) { cv[t] = ts[0][ii] + ts[1][jj]; cc[t] = ii * 32 + jj; }
        else         { cv[t] = -INFINITY;             cc[t] = 0x7fffffff;  }
    }

    unsigned used2 = 0;
    float mval = 0.f, myval = -INFINITY;
    int mycombo = 0;
    for (int it = 0; it < KNN; ++it) {
        float bv = -INFINITY; int bc = 0x7fffffff;
        #pragma unroll
        for (int t = 0; t < 2; ++t) {
            const bool live = !((used2 >> t) & 1u);
            const bool better = live &&
                (cv[t] > bv || (cv[t] == bv && cc[t] < bc));
            bv = better ? cv[t] : bv;
            bc = better ? cc[t] : bc;
        }
        float m = bv;
        #pragma unroll
        for (int off = 32; off; off >>= 1) m = fmaxf(m, __shfl_xor(m, off));
        const unsigned long long bal = __ballot(bv == m);
        int combo;
        if (__popcll(bal) == 1) {
            combo = __shfl(bc, (int)(__ffsll(bal) - 1));
        } else {
            unsigned cm = (bv == m) ? (unsigned)bc : 0xffffffffu;
            #pragma unroll
            for (int off = 32; off; off >>= 1) cm = min(cm, __shfl_xor(cm, off));
            combo = (int)cm;
        }
        if (it == 0) mval = m;
        if (lane == it) { myval = m; mycombo = combo; }
        #pragma unroll
        for (int t = 0; t < 2; ++t)
            if (cc[t] == combo) used2 |= 1u << t;
    }

    const float ew = (lane < KNN) ? expf(myval - mval) : 0.f;
    float ssum = ew;
    #pragma unroll
    for (int off = 32; off; off >>= 1) ssum += __shfl_xor(ssum, off);
    if (lane < KNN) {
        const int i1 = ti[0][mycombo >> 5];
        const int i2 = ti[1][mycombo & 31];
        w_out[(size_t)nh * KNN + lane] = ew / ssum;
        idx_out[(size_t)nh * KNN + lane] = i1 * NKEYS + i2;
    }
}

// =========== weighted embedding-bag gather + gate -> bf16 hi/lo out0 =======
__global__ __launch_bounds__(256)
void gather_kernel(const float* __restrict__ values,
                   const float* __restrict__ w, const int* __restrict__ idx,
                   const float* __restrict__ gate,
                   unsigned short* __restrict__ o0h, unsigned short* __restrict__ o0l)
{
    const int n = blockIdx.x;
    const int t = threadIdx.x;
    __shared__ float sw[HEADS * KNN];
    __shared__ int   sidx[HEADS * KNN];
    if (t < HEADS * KNN) {
        sw[t]   = w[(size_t)n * HEADS * KNN + t];
        sidx[t] = idx[(size_t)n * HEADS * KNN + t];
    }
    __syncthreads();
    const int d0 = t * 2;
    float2 acc = {0.f, 0.f};
    #pragma unroll 8
    for (int k = 0; k < HEADS * KNN; ++k) {
        const float2 v = *(const float2*)(values + (size_t)sidx[k] * DOUT + d0);
        const float ww = sw[k];
        acc.x = fmaf(ww, v.x, acc.x);
        acc.y = fmaf(ww, v.y, acc.y);
    }
    const float2 g = *(const float2*)(gate + (size_t)n * DOUT + d0);
    const float vx = acc.x * g.x;
    const float vy = acc.y * g.y;
    ushort2 h, l;
    h.x = f2bf(vx); l.x = f2bf(vx - bf2f(h.x));
    h.y = f2bf(vy); l.y = f2bf(vy - bf2f(h.y));
    *(ushort2*)(o0h + (size_t)n * DOUT + d0) = h;
    *(ushort2*)(o0l + (size_t)n * DOUT + d0) = l;
}

// =========== final projection: out = out0 @ Wv^T + bv (3-term MFMA) ========
__global__ __launch_bounds__(256)
void mfma_out(const unsigned short* __restrict__ o0h, const unsigned short* __restrict__ o0l,
              const unsigned short* __restrict__ vh, const unsigned short* __restrict__ vm,
              const float* __restrict__ bv, float* __restrict__ out)
{
    __shared__ __align__(16) unsigned short Al[64 * 64];
    __shared__ __align__(16) unsigned short Bl[64 * 64];
    const int tid = threadIdx.x;
    const int wid = tid >> 6, lane = tid & 63;
    const int r16 = lane & 15, kc = lane >> 4;
    const int wr = wid >> 1, wc = wid & 1;
    const int m0 = blockIdx.x * 64, n0 = blockIdx.y * 64;
    const int srow = tid >> 2;
    const int skb  = (tid & 3) << 4;
    const unsigned swzw = (unsigned)((srow & 7) << 4);

    f32x4 acc[2][2] = {};
    #pragma unroll
    for (int term = 0; term < 3; ++term) {
        const unsigned short* Ag = ((term == 2) ? o0l : o0h) + (size_t)(m0 + srow) * DOUT + skb;
        const unsigned short* Bg = ((term == 1) ? vm : vh) + (size_t)(n0 + srow) * DOUT + skb;
        for (int k0 = 0; k0 < DOUT; k0 += 64) {
            __syncthreads();
            const uint4 va0 = *(const uint4*)(Ag + k0);
            const uint4 va1 = *(const uint4*)(Ag + k0 + 8);
            const uint4 vb0 = *(const uint4*)(Bg + k0);
            const uint4 vb1 = *(const uint4*)(Bg + k0 + 8);
            const unsigned b0 = (unsigned)(srow * 128 + skb * 2) ^ swzw;
            const unsigned b1 = (unsigned)(srow * 128 + skb * 2 + 16) ^ swzw;
            *(uint4*)((char*)Al + b0) = va0; *(uint4*)((char*)Al + b1) = va1;
            *(uint4*)((char*)Bl + b0) = vb0; *(uint4*)((char*)Bl + b1) = vb1;
            __syncthreads();
            #pragma unroll
            for (int ks = 0; ks < 2; ++ks) {
                bf16x8 af[2], bf[2];
                #pragma unroll
                for (int f = 0; f < 2; ++f) {
                    const int am = wr * 32 + f * 16 + r16;
                    af[f] = *(const bf16x8*)((const char*)Al +
                        ((unsigned)(am * 128 + ks * 64 + kc * 16) ^ ((am & 7) << 4)));
                    const int bn = wc * 32 + f * 16 + r16;
                    bf[f] = *(const bf16x8*)((const char*)Bl +
                        ((unsigned)(bn * 128 + ks * 64 + kc * 16) ^ ((bn & 7) << 4)));
                }
                #pragma unroll
                for (int fm = 0; fm < 2; ++fm)
                    #pragma unroll
                    for (int fn = 0; fn < 2; ++fn)
                        acc[fm][fn] = __builtin_amdgcn_mfma_f32_16x16x32_bf16(
                            af[fm], bf[fn], acc[fm][fn], 0, 0, 0);
            }
        }
    }

    #pragma unroll
    for (int fm = 0; fm < 2; ++fm) {
        const int row = m0 + wr * 32 + fm * 16 + kc * 4;
        #pragma unroll
        for (int fn = 0; fn < 2; ++fn) {
            const int col = n0 + wc * 32 + fn * 16 + r16;
            const float b = bv[col];
            #pragma unroll
            for (int r = 0; r < 4; ++r)
                out[(size_t)(row + r) * DOUT + col] = acc[fm][fn][r] + b;
        }
    }
}

}  // namespace

extern "C" void kernel_launch(void* const* d_in, const int* in_sizes, int n_in,
                              void* d_out, int out_size, void* d_ws, size_t ws_size,
                              hipStream_t stream)
{
    const float* x      = (const float*)d_in[0];
    const float* Wq     = (const float*)d_in[1];
    const float* bq     = (const float*)d_in[2];
    const float* keys   = (const float*)d_in[3];
    const float* values = (const float*)d_in[4];
    const float* Wsw    = (const float*)d_in[5];
    const float* bsw    = (const float*)d_in[6];
    const float* Wv     = (const float*)d_in[7];
    const float* bv     = (const float*)d_in[8];
    float* out = (float*)d_out;

    // workspace layout (bf16 arrays, all 16B-aligned by construction)
    unsigned short* qh  = (unsigned short*)d_ws;                      // 8MB
    unsigned short* qm  = qh + (size_t)NROWS * HEADS * KDIM;          // 8MB
    unsigned short* ql  = qm + (size_t)NROWS * HEADS * KDIM;          // 8MB
    float*          s   = (float*)(ql + (size_t)NROWS * HEADS * KDIM); // 32MB
    unsigned short* xh  = (unsigned short*)(s + (size_t)NROWS * HEADS * 2 * NKEYS);
    unsigned short* xm  = xh + (size_t)NROWS * DIN;
    unsigned short* xl  = xm + (size_t)NROWS * DIN;
    unsigned short* wh  = xl + (size_t)NROWS * DIN;
    unsigned short* wm  = wh + (size_t)DOUT * DIN;
    unsigned short* kh  = wm + (size_t)DOUT * DIN;
    unsigned short* km  = kh + (size_t)8 * NKEYS * HALFD;
    unsigned short* kl  = km + (size_t)8 * NKEYS * HALFD;
    unsigned short* vh  = kl + (size_t)8 * NKEYS * HALFD;
    unsigned short* vm  = vh + (size_t)DOUT * DOUT;
    unsigned short* qwh = vm + (size_t)DOUT * DOUT;
    unsigned short* qwm = qwh + (size_t)HEADS * KDIM * DIN;
    unsigned short* qwl = qwm + (size_t)HEADS * KDIM * DIN;
    float*          wsc = (float*)(qwl + (size_t)HEADS * KDIM * DIN);
    int*            idxb = (int*)(wsc + (size_t)NROWS * HEADS * KNN);
    float*          gate = (float*)(idxb + (size_t)NROWS * HEADS * KNN);
    unsigned short* o0h  = (unsigned short*)(gate + (size_t)NROWS * DOUT);
    unsigned short* o0l  = o0h + (size_t)NROWS * DOUT;

    const dim3 blk(256);

    // 1) splits: x/keys/Wq 3-way, Wsw/Wv 2-way
    split6<<<dim3(1024, 1, 5), blk, 0, stream>>>(
        x, Wsw, keys, Wv, Wq,
        xh, xm, xl, wh, wm, kh, km, kl, vh, vm, qwh, qwm, qwl);

    // 2) q = x @ Wq^T + bq  (6-term triple-split MFMA) -> 3-way bf16 split
    mfma_q<<<dim3(16, 32), blk, 0, stream>>>(
        xh, xm, xl, qwh, qwm, qwl, bq, qh, qm, ql);

    // 3) scores (z<8, 6-term triple-split MFMA) + gate (z==8, 3-term)
    mfma_sg<<<dim3(16, 4, 9), blk, 0, stream>>>(
        qh, qm, ql, kh, km, kl, xh, xm, wh, wm, bsw, s, gate);

    // 4) tau-select -> bitonic exact top-32 -> stage 2 + softmax
    topk4<<<dim3(NROWS * HEADS), dim3(64), 0, stream>>>(s, wsc, idxb);

    // 5) out0 = (sum_k w*values[idx]) * gate  -> bf16 hi/lo
    gather_kernel<<<dim3(NROWS), blk, 0, stream>>>(
        values, wsc, idxb, gate, o0h, o0l);

    // 6) out = out0 @ Wv^T + bv  (3-term split MFMA)
    mfma_out<<<dim3(32, 8), blk, 0, stream>>>(o0h, o0l, vh, vm, bv, out);
}

// Round 13
// 250.297 us; speedup vs baseline: 1.2499x; 1.2499x over previous
//
#include <hip/hip_runtime.h>
#include <math.h>

namespace {

constexpr int NROWS = 2048;   // B*T
constexpr int DIN   = 512;
constexpr int DOUT  = 512;
constexpr int HEADS = 4;
constexpr int KDIM  = 512;
constexpr int HALFD = 256;
constexpr int NKEYS = 512;
constexpr int KNN   = 32;

typedef short bf16x8 __attribute__((ext_vector_type(8)));
typedef float f32x4  __attribute__((ext_vector_type(4)));

__device__ inline unsigned short f2bf(float f) {   // round-to-nearest-even
    unsigned u = __float_as_uint(f);
    unsigned r = u + 0x7FFFu + ((u >> 16) & 1u);
    return (unsigned short)(r >> 16);
}
__device__ inline float bf2f(unsigned short h) {
    return __uint_as_float((unsigned)h << 16);
}
__device__ inline unsigned fmap(float f) {
    unsigned u = __float_as_uint(f);
    return (u & 0x80000000u) ? ~u : (u | 0x80000000u);
}
__device__ inline float funmap(unsigned m) {
    unsigned u = (m & 0x80000000u) ? (m & 0x7FFFFFFFu) : ~m;
    return __uint_as_float(u);
}
__device__ inline unsigned long long shflxor64(unsigned long long x, int m) {
    unsigned lo = (unsigned)x, hi = (unsigned)(x >> 32);
    lo = __shfl_xor(lo, m);
    hi = __shfl_xor(hi, m);
    return ((unsigned long long)hi << 32) | lo;
}
// full 64-lane bitonic sort, descending by u64 key; lane l ends with rank-l
__device__ inline unsigned long long bitonic64_desc(unsigned long long v, int lane) {
    #pragma unroll
    for (int k = 2; k <= 64; k <<= 1) {
        #pragma unroll
        for (int j = k >> 1; j > 0; j >>= 1) {
            const unsigned long long o = shflxor64(v, j);
            const bool keepMax = (((lane & j) == 0) == ((lane & k) == 0));
            const bool oGreater = o > v;
            v = (keepMax == oGreater) ? o : v;
        }
    }
    return v;
}

// ====== splits: x 3-way (z0), Wsw 2-way (z1), keys 3-way (z2),
//                Wv 2-way (z3), Wq 3-way (z4)
__global__ __launch_bounds__(256)
void split6(const float* __restrict__ x, const float* __restrict__ wsw,
            const float* __restrict__ keys, const float* __restrict__ wv,
            const float* __restrict__ wq,
            unsigned short* __restrict__ xh, unsigned short* __restrict__ xm,
            unsigned short* __restrict__ xl,
            unsigned short* __restrict__ wh, unsigned short* __restrict__ wm,
            unsigned short* __restrict__ kh, unsigned short* __restrict__ km,
            unsigned short* __restrict__ kl,
            unsigned short* __restrict__ vh, unsigned short* __restrict__ vm,
            unsigned short* __restrict__ qwh, unsigned short* __restrict__ qwm,
            unsigned short* __restrict__ qwl)
{
    const int z = blockIdx.z;
    const int i = (blockIdx.x * 256 + threadIdx.x) * 4;
    const bool three = (z == 0) || (z == 2) || (z == 4);
    const float* src = (z == 0) ? x : (z == 1) ? wsw : (z == 2) ? keys
                     : (z == 3) ? wv : wq;
    unsigned short* ph = (z == 0) ? xh : (z == 1) ? wh : (z == 2) ? kh
                       : (z == 3) ? vh : qwh;
    unsigned short* pm = (z == 0) ? xm : (z == 1) ? wm : (z == 2) ? km
                       : (z == 3) ? vm : qwm;
    unsigned short* pl = (z == 0) ? xl : (z == 2) ? kl : qwl;
    const int n = (z == 1 || z == 3) ? 262144 : 1048576;
    if (i >= n) return;
    const float4 v = *(const float4*)(src + i);
    ushort4 oh, om, ol;
    float r;
    oh.x = f2bf(v.x); r = v.x - bf2f(oh.x); om.x = f2bf(r); ol.x = f2bf(r - bf2f(om.x));
    oh.y = f2bf(v.y); r = v.y - bf2f(oh.y); om.y = f2bf(r); ol.y = f2bf(r - bf2f(om.y));
    oh.z = f2bf(v.z); r = v.z - bf2f(oh.z); om.z = f2bf(r); ol.z = f2bf(r - bf2f(om.z));
    oh.w = f2bf(v.w); r = v.w - bf2f(oh.w); om.w = f2bf(r); ol.w = f2bf(r - bf2f(om.w));
    *(ushort4*)(ph + i) = oh;
    *(ushort4*)(pm + i) = om;
    if (three) *(ushort4*)(pl + i) = ol;
}

// staging: 128-row panel (4 uint4/thread) and 64-row panel (2 uint4/thread)
#define STAGE128(buf, G)                                                     \
    _Pragma("unroll")                                                        \
    for (int j = 0; j < 4; ++j) {                                            \
        const uint4 v_ = *(const uint4*)((G) + k0 + j * 8);                  \
        const unsigned b_ = (unsigned)(srow * 128 + (skb + j * 8) * 2) ^ swzw;\
        *(uint4*)((char*)(buf) + b_) = v_;                                   \
    }
#define STAGE64(buf, G)                                                      \
    _Pragma("unroll")                                                        \
    for (int j = 0; j < 2; ++j) {                                            \
        const uint4 v_ = *(const uint4*)((G) + k0 + j * 8);                  \
        const unsigned b_ = (unsigned)(srowB * 128 + (skbB + j * 8) * 2)     \
                          ^ ((srowB & 7) << 4);                              \
        *(uint4*)((char*)(buf) + b_) = v_;                                   \
    }

// ===== q = x @ Wq^T + bq, 6-term triple-split MFMA, variant-resident =======
// 128x64 tile, grid (16,32)=512 blocks.  LDS 48 KB.
__global__ __launch_bounds__(256)
void mfma_q(const unsigned short* __restrict__ xh, const unsigned short* __restrict__ xm,
            const unsigned short* __restrict__ xl,
            const unsigned short* __restrict__ WH, const unsigned short* __restrict__ WM,
            const unsigned short* __restrict__ WL,
            const float* __restrict__ bias,
            unsigned short* __restrict__ qh, unsigned short* __restrict__ qm,
            unsigned short* __restrict__ ql)
{
    __shared__ __align__(16) unsigned short Ah[128 * 64];
    __shared__ __align__(16) unsigned short Ax[128 * 64];
    __shared__ __align__(16) unsigned short Bh[64 * 64];
    __shared__ __align__(16) unsigned short Bx[64 * 64];
    const int tid = threadIdx.x;
    const int wid = tid >> 6, lane = tid & 63;
    const int r16 = lane & 15, kc = lane >> 4;
    const int wr = wid >> 1, wc = wid & 1;
    const int m0 = blockIdx.x * 128, n0 = blockIdx.y * 64;
    const int srow  = tid >> 1;          // 0..127
    const int skb   = (tid & 1) << 5;    // 0/32
    const int srowB = tid >> 2;          // 0..63
    const int skbB  = (tid & 3) << 4;    // 0,16,32,48
    const unsigned swzw = (unsigned)((srow & 7) << 4);

    const unsigned short* Agh = xh + (size_t)(m0 + srow) * DIN + skb;
    const unsigned short* Agm = xm + (size_t)(m0 + srow) * DIN + skb;
    const unsigned short* Agl = xl + (size_t)(m0 + srow) * DIN + skb;
    const unsigned short* Bgh = WH + (size_t)(n0 + srowB) * DIN + skbB;
    const unsigned short* Bgm = WM + (size_t)(n0 + srowB) * DIN + skbB;
    const unsigned short* Bgl = WL + (size_t)(n0 + srowB) * DIN + skbB;

    f32x4 acc[4][2] = {};

#define COMPUTE_Q(bufA, bufB)                                                \
    _Pragma("unroll")                                                        \
    for (int ks = 0; ks < 2; ++ks) {                                         \
        bf16x8 af[4], bfr[2];                                                \
        _Pragma("unroll")                                                    \
        for (int f = 0; f < 4; ++f) {                                        \
            const int am = wr * 64 + f * 16 + r16;                           \
            af[f] = *(const bf16x8*)((const char*)(bufA) +                   \
                ((unsigned)(am * 128 + ks * 64 + kc * 16) ^ ((am & 7) << 4)));\
        }                                                                    \
        _Pragma("unroll")                                                    \
        for (int f = 0; f < 2; ++f) {                                        \
            const int bn = wc * 32 + f * 16 + r16;                           \
            bfr[f] = *(const bf16x8*)((const char*)(bufB) +                  \
                ((unsigned)(bn * 128 + ks * 64 + kc * 16) ^ ((bn & 7) << 4)));\
        }                                                                    \
        _Pragma("unroll")                                                    \
        for (int fm = 0; fm < 4; ++fm)                                       \
            _Pragma("unroll")                                                \
            for (int fn = 0; fn < 2; ++fn)                                   \
                acc[fm][fn] = __builtin_amdgcn_mfma_f32_16x16x32_bf16(       \
                    af[fm], bfr[fn], acc[fm][fn], 0, 0, 0);                  \
    }

    for (int k0 = 0; k0 < DIN; k0 += 64) {
        STAGE128(Ah, Agh) STAGE128(Ax, Agm)
        STAGE64(Bh, Bgh)  STAGE64(Bx, Bgm)
        __syncthreads();
        COMPUTE_Q(Ah, Bh)     // hh
        COMPUTE_Q(Ah, Bx)     // hm
        COMPUTE_Q(Ax, Bh)     // mh
        COMPUTE_Q(Ax, Bx)     // mm
        __syncthreads();
        STAGE128(Ax, Agl) STAGE64(Bx, Bgl)
        __syncthreads();
        COMPUTE_Q(Ah, Bx)     // hl
        COMPUTE_Q(Ax, Bh)     // lh
        __syncthreads();
    }
#undef COMPUTE_Q

    #pragma unroll
    for (int fm = 0; fm < 4; ++fm) {
        const int row = m0 + wr * 64 + fm * 16 + kc * 4;
        #pragma unroll
        for (int fn = 0; fn < 2; ++fn) {
            const int col = n0 + wc * 32 + fn * 16 + r16;
            const float b = bias[col];
            #pragma unroll
            for (int r = 0; r < 4; ++r) {
                const float o = acc[fm][fn][r] + b;
                const unsigned short h = f2bf(o);
                const float rr = o - bf2f(h);
                const unsigned short m = f2bf(rr);
                const unsigned short l = f2bf(rr - bf2f(m));
                const size_t off = (size_t)(row + r) * (HEADS * KDIM) + col;
                qh[off] = h; qm[off] = m; ql[off] = l;
            }
        }
    }
}

// ======= scores (z<8, 6-term) + gate (z==8, 3-term), variant-resident ======
// 128x128 tile, 4 waves, BK=64, T2 swizzle.  LDS 64 KB.
__global__ __launch_bounds__(256)
void mfma_sg(const unsigned short* __restrict__ qh, const unsigned short* __restrict__ qm,
             const unsigned short* __restrict__ ql,
             const unsigned short* __restrict__ kh, const unsigned short* __restrict__ km,
             const unsigned short* __restrict__ kl,
             const unsigned short* __restrict__ xh, const unsigned short* __restrict__ xm,
             const unsigned short* __restrict__ wh, const unsigned short* __restrict__ wm,
             const float* __restrict__ bsw,
             float* __restrict__ s, float* __restrict__ gate)
{
    __shared__ __align__(16) unsigned short Ah[128 * 64];
    __shared__ __align__(16) unsigned short Bh[128 * 64];
    __shared__ __align__(16) unsigned short Ax[128 * 64];
    __shared__ __align__(16) unsigned short Bx[128 * 64];
    const int tid  = threadIdx.x;
    const int wid  = tid >> 6, lane = tid & 63;
    const int r16  = lane & 15, kc = lane >> 4;
    const int wr   = wid >> 1, wc = wid & 1;
    const int z    = blockIdx.z;
    const int bx   = blockIdx.x, by = blockIdx.y;
    const int srow = tid >> 1;
    const int skb  = (tid & 1) << 5;
    const unsigned swzw = (unsigned)((srow & 7) << 4);

    const unsigned short *Agh, *Agm, *Agl, *Bgh, *Bgm, *Bgl;
    int K;
    if (z < 8) {
        const size_t aoff = (size_t)(bx * 128 + srow) * (HEADS * KDIM)
                          + (z >> 1) * KDIM + (z & 1) * HALFD + skb;
        const size_t boff = ((size_t)z * NKEYS + by * 128 + srow) * HALFD + skb;
        Agh = qh + aoff; Agm = qm + aoff; Agl = ql + aoff;
        Bgh = kh + boff; Bgm = km + boff; Bgl = kl + boff;
        K = HALFD;
    } else {
        const size_t aoff = (size_t)(bx * 128 + srow) * DIN + skb;
        const size_t boff = (size_t)(by * 128 + srow) * DIN + skb;
        Agh = xh + aoff; Agm = xm + aoff; Agl = nullptr;
        Bgh = wh + boff; Bgm = wm + boff; Bgl = nullptr;
        K = DIN;
    }

    f32x4 acc[4][4] = {};

#define COMPUTE_SG(bufA, bufB)                                               \
    _Pragma("unroll")                                                        \
    for (int ks = 0; ks < 2; ++ks) {                                         \
        bf16x8 af[4], bf[4];                                                 \
        _Pragma("unroll")                                                    \
        for (int f = 0; f < 4; ++f) {                                        \
            const int am = wr * 64 + f * 16 + r16;                           \
            af[f] = *(const bf16x8*)((const char*)(bufA) +                   \
                ((unsigned)(am * 128 + ks * 64 + kc * 16) ^ ((am & 7) << 4)));\
            const int bn = wc * 64 + f * 16 + r16;                           \
            bf[f] = *(const bf16x8*)((const char*)(bufB) +                   \
                ((unsigned)(bn * 128 + ks * 64 + kc * 16) ^ ((bn & 7) << 4)));\
        }                                                                    \
        _Pragma("unroll")                                                    \
        for (int fm = 0; fm < 4; ++fm)                                       \
            _Pragma("unroll")                                                \
            for (int fn = 0; fn < 4; ++fn)                                   \
                acc[fm][fn] = __builtin_amdgcn_mfma_f32_16x16x32_bf16(       \
                    af[fm], bf[fn], acc[fm][fn], 0, 0, 0);                   \
    }

    for (int k0 = 0; k0 < K; k0 += 64) {
        STAGE128(Ah, Agh) STAGE128(Bh, Bgh)
        STAGE128(Ax, Agm) STAGE128(Bx, Bgm)
        __syncthreads();
        COMPUTE_SG(Ah, Bh)      // hh
        COMPUTE_SG(Ah, Bx)      // hm
        COMPUTE_SG(Ax, Bh)      // mh
        if (z < 8) {
            COMPUTE_SG(Ax, Bx)  // mm
            __syncthreads();
            STAGE128(Ax, Agl) STAGE128(Bx, Bgl)
            __syncthreads();
            COMPUTE_SG(Ah, Bx)  // hl
            COMPUTE_SG(Ax, Bh)  // lh
        }
        __syncthreads();
    }
#undef COMPUTE_SG

    #pragma unroll
    for (int fm = 0; fm < 4; ++fm) {
        const int row = bx * 128 + wr * 64 + fm * 16 + kc * 4;
        #pragma unroll
        for (int fn = 0; fn < 4; ++fn) {
            const int col = by * 128 + wc * 64 + fn * 16 + r16;
            #pragma unroll
            for (int r = 0; r < 4; ++r) {
                float v = acc[fm][fn][r];
                if (z < 8) {
                    s[(size_t)(row + r) * (HEADS * 2 * NKEYS) + z * NKEYS + col] = v;
                } else {
                    v += bsw[col];
                    v = v / (1.f + expf(-v));
                    gate[(size_t)(row + r) * DOUT + col] = v;
                }
            }
        }
    }
}

// ====== topk4 (R11-proven): tau-select [32,64] -> bitonic top-32 -> stage 2
__global__ __launch_bounds__(64)
void topk4(const float* __restrict__ s,
           float* __restrict__ w_out, int* __restrict__ idx_out)
{
    const int nh   = blockIdx.x;
    const int lane = threadIdx.x;
    const int sub  = lane >> 5;
    const int sl   = lane & 31;
    __shared__ unsigned long long pkl[2][64];
    __shared__ float ts[2][KNN];
    __shared__ int   ti[2][KNN];

    const float* sb = s + (size_t)nh * (2 * NKEYS) + sub * NKEYS;
    unsigned u[16];
    #pragma unroll
    for (int i = 0; i < 16; ++i) u[i] = fmap(sb[i * 32 + sl]);

    unsigned lo = 0, hi = 0xFFFFFFFFu, tau = 0;
    bool found = false;
    for (int iter = 0; iter < 30; ++iter) {
        if (__all(found)) break;
        const unsigned mid = lo + ((hi - lo) >> 1);
        int c = 0;
        #pragma unroll
        for (int i = 0; i < 16; ++i) c += (u[i] >= mid) ? 1 : 0;
        #pragma unroll
        for (int off = 1; off <= 16; off <<= 1) c += __shfl_xor(c, off);
        if (!found) {
            if (c >= 32 && c <= 64) { tau = mid; found = true; }
            else if (c > 64) lo = mid + 1;
            else hi = mid - 1;
        }
    }
    if (!found) tau = lo;

    pkl[0][lane] = 0ull;
    pkl[1][lane] = 0ull;
    __syncthreads();
    unsigned msk = 0;
    #pragma unroll
    for (int i = 0; i < 16; ++i) msk |= (u[i] >= tau ? 1u : 0u) << i;
    int mc = __popc(msk);
    int pfx = mc;
    #pragma unroll
    for (int d = 1; d <= 16; d <<= 1) {
        const int t = __shfl_up(pfx, d);
        if (sl >= d) pfx += t;
    }
    int slot = pfx - mc;
    #pragma unroll
    for (int i = 0; i < 16; ++i)
        if ((msk >> i) & 1u) {
            if (slot < 64)
                pkl[sub][slot] = ((unsigned long long)u[i] << 32)
                               | (unsigned)(~((i << 5) | sl));
            ++slot;
        }
    __syncthreads();

    #pragma unroll
    for (int p = 0; p < 2; ++p) {
        unsigned long long v = bitonic64_desc(pkl[p][lane], lane);
        if (lane < KNN) {
            ts[p][lane] = funmap((unsigned)(v >> 32));
            ti[p][lane] = (int)(~(unsigned)v) & (NKEYS - 1);
        }
    }
    __syncthreads();

    float cv[2]; int cc[2];
    #pragma unroll
    for (int t = 0; t < 2; ++t) {
        const int c = t * 64 + lane;
        int ii = -1, jj = 0, off = 0;
        #pragma unroll
        for (int i = 0; i < 32; ++i) {
            const int cnt = 32 / (i + 1);
            const bool in = (c >= off) && (c < off + cnt);
            ii = in ? i : ii;
            jj = in ? c - off : jj;
            off += cnt;
        }
        if (ii >= 0) { cv[t] = ts[0][ii] + ts[1][jj]; cc[t] = ii * 32 + jj; }
        else         { cv[t] = -INFINITY;             cc[t] = 0x7fffffff;  }
    }

    unsigned used2 = 0;
    float mval = 0.f, myval = -INFINITY;
    int mycombo = 0;
    for (int it = 0; it < KNN; ++it) {
        float bv = -INFINITY; int bc = 0x7fffffff;
        #pragma unroll
        for (int t = 0; t < 2; ++t) {
            const bool live = !((used2 >> t) & 1u);
            const bool better = live &&
                (cv[t] > bv || (cv[t] == bv && cc[t] < bc));
            bv = better ? cv[t] : bv;
            bc = better ? cc[t] : bc;
        }
        float m = bv;
        #pragma unroll
        for (int off = 32; off; off >>= 1) m = fmaxf(m, __shfl_xor(m, off));
        const unsigned long long bal = __ballot(bv == m);
        int combo;
        if (__popcll(bal) == 1) {
            combo = __shfl(bc, (int)(__ffsll(bal) - 1));
        } else {
            unsigned cm = (bv == m) ? (unsigned)bc : 0xffffffffu;
            #pragma unroll
            for (int off = 32; off; off >>= 1) cm = min(cm, __shfl_xor(cm, off));
            combo = (int)cm;
        }
        if (it == 0) mval = m;
        if (lane == it) { myval = m; mycombo = combo; }
        #pragma unroll
        for (int t = 0; t < 2; ++t)
            if (cc[t] == combo) used2 |= 1u << t;
    }

    const float ew = (lane < KNN) ? expf(myval - mval) : 0.f;
    float ssum = ew;
    #pragma unroll
    for (int off = 32; off; off >>= 1) ssum += __shfl_xor(ssum, off);
    if (lane < KNN) {
        const int i1 = ti[0][mycombo >> 5];
        const int i2 = ti[1][mycombo & 31];
        w_out[(size_t)nh * KNN + lane] = ew / ssum;
        idx_out[(size_t)nh * KNN + lane] = i1 * NKEYS + i2;
    }
}

// =========== weighted embedding-bag gather + gate -> bf16 hi/lo out0 =======
__global__ __launch_bounds__(256)
void gather_kernel(const float* __restrict__ values,
                   const float* __restrict__ w, const int* __restrict__ idx,
                   const float* __restrict__ gate,
                   unsigned short* __restrict__ o0h, unsigned short* __restrict__ o0l)
{
    const int n = blockIdx.x;
    const int t = threadIdx.x;
    __shared__ float sw[HEADS * KNN];
    __shared__ int   sidx[HEADS * KNN];
    if (t < HEADS * KNN) {
        sw[t]   = w[(size_t)n * HEADS * KNN + t];
        sidx[t] = idx[(size_t)n * HEADS * KNN + t];
    }
    __syncthreads();
    const int d0 = t * 2;
    float2 acc = {0.f, 0.f};
    #pragma unroll 8
    for (int k = 0; k < HEADS * KNN; ++k) {
        const float2 v = *(const float2*)(values + (size_t)sidx[k] * DOUT + d0);
        const float ww = sw[k];
        acc.x = fmaf(ww, v.x, acc.x);
        acc.y = fmaf(ww, v.y, acc.y);
    }
    const float2 g = *(const float2*)(gate + (size_t)n * DOUT + d0);
    const float vx = acc.x * g.x;
    const float vy = acc.y * g.y;
    ushort2 h, l;
    h.x = f2bf(vx); l.x = f2bf(vx - bf2f(h.x));
    h.y = f2bf(vy); l.y = f2bf(vy - bf2f(h.y));
    *(ushort2*)(o0h + (size_t)n * DOUT + d0) = h;
    *(ushort2*)(o0l + (size_t)n * DOUT + d0) = l;
}

// =========== final projection: out = out0 @ Wv^T + bv (3-term MFMA) ========
__global__ __launch_bounds__(256)
void mfma_out(const unsigned short* __restrict__ o0h, const unsigned short* __restrict__ o0l,
              const unsigned short* __restrict__ vh, const unsigned short* __restrict__ vm,
              const float* __restrict__ bv, float* __restrict__ out)
{
    __shared__ __align__(16) unsigned short Al[64 * 64];
    __shared__ __align__(16) unsigned short Bl[64 * 64];
    const int tid = threadIdx.x;
    const int wid = tid >> 6, lane = tid & 63;
    const int r16 = lane & 15, kc = lane >> 4;
    const int wr = wid >> 1, wc = wid & 1;
    const int m0 = blockIdx.x * 64, n0 = blockIdx.y * 64;
    const int srow = tid >> 2;
    const int skb  = (tid & 3) << 4;
    const unsigned swzw = (unsigned)((srow & 7) << 4);

    f32x4 acc[2][2] = {};
    #pragma unroll
    for (int term = 0; term < 3; ++term) {
        const unsigned short* Ag = ((term == 2) ? o0l : o0h) + (size_t)(m0 + srow) * DOUT + skb;
        const unsigned short* Bg = ((term == 1) ? vm : vh) + (size_t)(n0 + srow) * DOUT + skb;
        for (int k0 = 0; k0 < DOUT; k0 += 64) {
            __syncthreads();
            const uint4 va0 = *(const uint4*)(Ag + k0);
            const uint4 va1 = *(const uint4*)(Ag + k0 + 8);
            const uint4 vb0 = *(const uint4*)(Bg + k0);
            const uint4 vb1 = *(const uint4*)(Bg + k0 + 8);
            const unsigned b0 = (unsigned)(srow * 128 + skb * 2) ^ swzw;
            const unsigned b1 = (unsigned)(srow * 128 + skb * 2 + 16) ^ swzw;
            *(uint4*)((char*)Al + b0) = va0; *(uint4*)((char*)Al + b1) = va1;
            *(uint4*)((char*)Bl + b0) = vb0; *(uint4*)((char*)Bl + b1) = vb1;
            __syncthreads();
            #pragma unroll
            for (int ks = 0; ks < 2; ++ks) {
                bf16x8 af[2], bf[2];
                #pragma unroll
                for (int f = 0; f < 2; ++f) {
                    const int am = wr * 32 + f * 16 + r16;
                    af[f] = *(const bf16x8*)((const char*)Al +
                        ((unsigned)(am * 128 + ks * 64 + kc * 16) ^ ((am & 7) << 4)));
                    const int bn = wc * 32 + f * 16 + r16;
                    bf[f] = *(const bf16x8*)((const char*)Bl +
                        ((unsigned)(bn * 128 + ks * 64 + kc * 16) ^ ((bn & 7) << 4)));
                }
                #pragma unroll
                for (int fm = 0; fm < 2; ++fm)
                    #pragma unroll
                    for (int fn = 0; fn < 2; ++fn)
                        acc[fm][fn] = __builtin_amdgcn_mfma_f32_16x16x32_bf16(
                            af[fm], bf[fn], acc[fm][fn], 0, 0, 0);
            }
        }
    }

    #pragma unroll
    for (int fm = 0; fm < 2; ++fm) {
        const int row = m0 + wr * 32 + fm * 16 + kc * 4;
        #pragma unroll
        for (int fn = 0; fn < 2; ++fn) {
            const int col = n0 + wc * 32 + fn * 16 + r16;
            const float b = bv[col];
            #pragma unroll
            for (int r = 0; r < 4; ++r)
                out[(size_t)(row + r) * DOUT + col] = acc[fm][fn][r] + b;
        }
    }
}

}  // namespace

extern "C" void kernel_launch(void* const* d_in, const int* in_sizes, int n_in,
                              void* d_out, int out_size, void* d_ws, size_t ws_size,
                              hipStream_t stream)
{
    const float* x      = (const float*)d_in[0];
    const float* Wq     = (const float*)d_in[1];
    const float* bq     = (const float*)d_in[2];
    const float* keys   = (const float*)d_in[3];
    const float* values = (const float*)d_in[4];
    const float* Wsw    = (const float*)d_in[5];
    const float* bsw    = (const float*)d_in[6];
    const float* Wv     = (const float*)d_in[7];
    const float* bv     = (const float*)d_in[8];
    float* out = (float*)d_out;

    // workspace layout (bf16 arrays, all 16B-aligned by construction)
    unsigned short* qh  = (unsigned short*)d_ws;                      // 8MB
    unsigned short* qm  = qh + (size_t)NROWS * HEADS * KDIM;          // 8MB
    unsigned short* ql  = qm + (size_t)NROWS * HEADS * KDIM;          // 8MB
    float*          s   = (float*)(ql + (size_t)NROWS * HEADS * KDIM); // 32MB
    unsigned short* xh  = (unsigned short*)(s + (size_t)NROWS * HEADS * 2 * NKEYS);
    unsigned short* xm  = xh + (size_t)NROWS * DIN;
    unsigned short* xl  = xm + (size_t)NROWS * DIN;
    unsigned short* wh  = xl + (size_t)NROWS * DIN;
    unsigned short* wm  = wh + (size_t)DOUT * DIN;
    unsigned short* kh  = wm + (size_t)DOUT * DIN;
    unsigned short* km  = kh + (size_t)8 * NKEYS * HALFD;
    unsigned short* kl  = km + (size_t)8 * NKEYS * HALFD;
    unsigned short* vh  = kl + (size_t)8 * NKEYS * HALFD;
    unsigned short* vm  = vh + (size_t)DOUT * DOUT;
    unsigned short* qwh = vm + (size_t)DOUT * DOUT;
    unsigned short* qwm = qwh + (size_t)HEADS * KDIM * DIN;
    unsigned short* qwl = qwm + (size_t)HEADS * KDIM * DIN;
    float*          wsc = (float*)(qwl + (size_t)HEADS * KDIM * DIN);
    int*            idxb = (int*)(wsc + (size_t)NROWS * HEADS * KNN);
    float*          gate = (float*)(idxb + (size_t)NROWS * HEADS * KNN);
    unsigned short* o0h  = (unsigned short*)(gate + (size_t)NROWS * DOUT);
    unsigned short* o0l  = o0h + (size_t)NROWS * DOUT;

    const dim3 blk(256);

    // 1) splits: x/keys/Wq 3-way, Wsw/Wv 2-way
    split6<<<dim3(1024, 1, 5), blk, 0, stream>>>(
        x, Wsw, keys, Wv, Wq,
        xh, xm, xl, wh, wm, kh, km, kl, vh, vm, qwh, qwm, qwl);

    // 2) q = x @ Wq^T + bq  (6-term, variant-resident) -> 3-way bf16 split
    mfma_q<<<dim3(16, 32), blk, 0, stream>>>(
        xh, xm, xl, qwh, qwm, qwl, bq, qh, qm, ql);

    // 3) scores (z<8, 6-term) + gate (z==8, 3-term), variant-resident
    mfma_sg<<<dim3(16, 4, 9), blk, 0, stream>>>(
        qh, qm, ql, kh, km, kl, xh, xm, wh, wm, bsw, s, gate);

    // 4) tau-select -> bitonic exact top-32 -> stage 2 + softmax
    topk4<<<dim3(NROWS * HEADS), dim3(64), 0, stream>>>(s, wsc, idxb);

    // 5) out0 = (sum_k w*values[idx]) * gate  -> bf16 hi/lo
    gather_kernel<<<dim3(NROWS), blk, 0, stream>>>(
        values, wsc, idxb, gate, o0h, o0l);

    // 6) out = out0 @ Wv^T + bv  (3-term split MFMA)
    mfma_out<<<dim3(32, 8), blk, 0, stream>>>(o0h, o0l, vh, vm, bv, out);
}

// Round 14
// 244.019 us; speedup vs baseline: 1.2821x; 1.0257x over previous
//
#include <hip/hip_runtime.h>
#include <math.h>

namespace {

constexpr int NROWS = 2048;   // B*T
constexpr int DIN   = 512;
constexpr int DOUT  = 512;
constexpr int HEADS = 4;
constexpr int KDIM  = 512;
constexpr int HALFD = 256;
constexpr int NKEYS = 512;
constexpr int KNN   = 32;

typedef short bf16x8 __attribute__((ext_vector_type(8)));
typedef float f32x4  __attribute__((ext_vector_type(4)));
typedef const __attribute__((address_space(1))) void gvoid_t;
typedef __attribute__((address_space(3))) void lvoid_t;

__device__ inline unsigned short f2bf(float f) {   // round-to-nearest-even
    unsigned u = __float_as_uint(f);
    unsigned r = u + 0x7FFFu + ((u >> 16) & 1u);
    return (unsigned short)(r >> 16);
}
__device__ inline float bf2f(unsigned short h) {
    return __uint_as_float((unsigned)h << 16);
}
__device__ inline unsigned fmap(float f) {
    unsigned u = __float_as_uint(f);
    return (u & 0x80000000u) ? ~u : (u | 0x80000000u);
}
__device__ inline float funmap(unsigned m) {
    unsigned u = (m & 0x80000000u) ? (m & 0x7FFFFFFFu) : ~m;
    return __uint_as_float(u);
}
__device__ inline unsigned long long shflxor64(unsigned long long x, int m) {
    unsigned lo = (unsigned)x, hi = (unsigned)(x >> 32);
    lo = __shfl_xor(lo, m);
    hi = __shfl_xor(hi, m);
    return ((unsigned long long)hi << 32) | lo;
}
// full 64-lane bitonic sort, descending by u64 key; lane l ends with rank-l
__device__ inline unsigned long long bitonic64_desc(unsigned long long v, int lane) {
    #pragma unroll
    for (int k = 2; k <= 64; k <<= 1) {
        #pragma unroll
        for (int j = k >> 1; j > 0; j >>= 1) {
            const unsigned long long o = shflxor64(v, j);
            const bool keepMax = (((lane & j) == 0) == ((lane & k) == 0));
            const bool oGreater = o > v;
            v = (keepMax == oGreater) ? o : v;
        }
    }
    return v;
}

// ====== splits: x 3-way (z0), Wsw 2-way (z1), keys 3-way (z2),
//                Wv 2-way (z3), Wq 3-way (z4)
__global__ __launch_bounds__(256)
void split6(const float* __restrict__ x, const float* __restrict__ wsw,
            const float* __restrict__ keys, const float* __restrict__ wv,
            const float* __restrict__ wq,
            unsigned short* __restrict__ xh, unsigned short* __restrict__ xm,
            unsigned short* __restrict__ xl,
            unsigned short* __restrict__ wh, unsigned short* __restrict__ wm,
            unsigned short* __restrict__ kh, unsigned short* __restrict__ km,
            unsigned short* __restrict__ kl,
            unsigned short* __restrict__ vh, unsigned short* __restrict__ vm,
            unsigned short* __restrict__ qwh, unsigned short* __restrict__ qwm,
            unsigned short* __restrict__ qwl)
{
    const int z = blockIdx.z;
    const int i = (blockIdx.x * 256 + threadIdx.x) * 4;
    const bool three = (z == 0) || (z == 2) || (z == 4);
    const float* src = (z == 0) ? x : (z == 1) ? wsw : (z == 2) ? keys
                     : (z == 3) ? wv : wq;
    unsigned short* ph = (z == 0) ? xh : (z == 1) ? wh : (z == 2) ? kh
                       : (z == 3) ? vh : qwh;
    unsigned short* pm = (z == 0) ? xm : (z == 1) ? wm : (z == 2) ? km
                       : (z == 3) ? vm : qwm;
    unsigned short* pl = (z == 0) ? xl : (z == 2) ? kl : qwl;
    const int n = (z == 1 || z == 3) ? 262144 : 1048576;
    if (i >= n) return;
    const float4 v = *(const float4*)(src + i);
    ushort4 oh, om, ol;
    float r;
    oh.x = f2bf(v.x); r = v.x - bf2f(oh.x); om.x = f2bf(r); ol.x = f2bf(r - bf2f(om.x));
    oh.y = f2bf(v.y); r = v.y - bf2f(oh.y); om.y = f2bf(r); ol.y = f2bf(r - bf2f(om.y));
    oh.z = f2bf(v.z); r = v.z - bf2f(oh.z); om.z = f2bf(r); ol.z = f2bf(r - bf2f(om.z));
    oh.w = f2bf(v.w); r = v.w - bf2f(oh.w); om.w = f2bf(r); ol.w = f2bf(r - bf2f(om.w));
    *(ushort4*)(ph + i) = oh;
    *(ushort4*)(pm + i) = om;
    if (three) *(ushort4*)(pl + i) = ol;
}

// ---- async stage: linear LDS dest + inverse-swizzled global source --------
// LDS chunk c (16B) of row r holds global chunk c ^ (r&7)  [== R13 layout].
// Each instruction: 64 lanes x 16B = 8 rows (rows have 128B = 8 chunks).
// AST128: 128-row panel, 16 instrs, 4/wave.  AST64: 64-row panel, 8, 2/wave.
#define AST128(buf, G, ldg)                                                  \
    _Pragma("unroll")                                                        \
    for (int ii_ = 0; ii_ < 4; ++ii_) {                                      \
        const int r0_ = (wid * 4 + ii_) * 8;                                 \
        const int row_ = r0_ + (lane >> 3);                                  \
        const int cs_ = (lane & 7) ^ (row_ & 7);                             \
        __builtin_amdgcn_global_load_lds(                                    \
            (gvoid_t*)((G) + (size_t)row_ * (ldg) + cs_ * 8),                \
            (lvoid_t*)((char*)(buf) + r0_ * 128), 16, 0, 0);                 \
    }
#define AST64(buf, G, ldg)                                                   \
    _Pragma("unroll")                                                        \
    for (int ii_ = 0; ii_ < 2; ++ii_) {                                      \
        const int r0_ = (wid * 2 + ii_) * 8;                                 \
        const int row_ = r0_ + (lane >> 3);                                  \
        const int cs_ = (lane & 7) ^ (row_ & 7);                             \
        __builtin_amdgcn_global_load_lds(                                    \
            (gvoid_t*)((G) + (size_t)row_ * (ldg) + cs_ * 8),                \
            (lvoid_t*)((char*)(buf) + r0_ * 128), 16, 0, 0);                 \
    }

// ===== q = x @ Wq^T + bq, 6-term triple-split MFMA, variant-resident =======
// 128x64 tile, grid (16,32)=512 blocks.  LDS 48 KB.  Async staging.
__global__ __launch_bounds__(256)
void mfma_q(const unsigned short* __restrict__ xh, const unsigned short* __restrict__ xm,
            const unsigned short* __restrict__ xl,
            const unsigned short* __restrict__ WH, const unsigned short* __restrict__ WM,
            const unsigned short* __restrict__ WL,
            const float* __restrict__ bias,
            unsigned short* __restrict__ qh, unsigned short* __restrict__ qm,
            unsigned short* __restrict__ ql)
{
    __shared__ __align__(16) unsigned short Ah[128 * 64];
    __shared__ __align__(16) unsigned short Ax[128 * 64];
    __shared__ __align__(16) unsigned short Bh[64 * 64];
    __shared__ __align__(16) unsigned short Bx[64 * 64];
    const int tid = threadIdx.x;
    const int wid = tid >> 6, lane = tid & 63;
    const int r16 = lane & 15, kc = lane >> 4;
    const int wr = wid >> 1, wc = wid & 1;
    const int m0 = blockIdx.x * 128, n0 = blockIdx.y * 64;

    const unsigned short* Agh = xh + (size_t)m0 * DIN;
    const unsigned short* Agm = xm + (size_t)m0 * DIN;
    const unsigned short* Agl = xl + (size_t)m0 * DIN;
    const unsigned short* Bgh = WH + (size_t)n0 * DIN;
    const unsigned short* Bgm = WM + (size_t)n0 * DIN;
    const unsigned short* Bgl = WL + (size_t)n0 * DIN;

    f32x4 acc[4][2] = {};

#define COMPUTE_Q(bufA, bufB)                                                \
    _Pragma("unroll")                                                        \
    for (int ks = 0; ks < 2; ++ks) {                                         \
        bf16x8 af[4], bfr[2];                                                \
        _Pragma("unroll")                                                    \
        for (int f = 0; f < 4; ++f) {                                        \
            const int am = wr * 64 + f * 16 + r16;                           \
            af[f] = *(const bf16x8*)((const char*)(bufA) +                   \
                ((unsigned)(am * 128 + ks * 64 + kc * 16) ^ ((am & 7) << 4)));\
        }                                                                    \
        _Pragma("unroll")                                                    \
        for (int f = 0; f < 2; ++f) {                                        \
            const int bn = wc * 32 + f * 16 + r16;                           \
            bfr[f] = *(const bf16x8*)((const char*)(bufB) +                  \
                ((unsigned)(bn * 128 + ks * 64 + kc * 16) ^ ((bn & 7) << 4)));\
        }                                                                    \
        _Pragma("unroll")                                                    \
        for (int fm = 0; fm < 4; ++fm)                                       \
            _Pragma("unroll")                                                \
            for (int fn = 0; fn < 2; ++fn)                                   \
                acc[fm][fn] = __builtin_amdgcn_mfma_f32_16x16x32_bf16(       \
                    af[fm], bfr[fn], acc[fm][fn], 0, 0, 0);                  \
    }

    for (int k0 = 0; k0 < DIN; k0 += 64) {
        AST128(Ah, Agh + k0, DIN) AST128(Ax, Agm + k0, DIN)
        AST64(Bh, Bgh + k0, DIN)  AST64(Bx, Bgm + k0, DIN)
        __syncthreads();
        COMPUTE_Q(Ah, Bh)     // hh
        COMPUTE_Q(Ah, Bx)     // hm
        COMPUTE_Q(Ax, Bh)     // mh
        COMPUTE_Q(Ax, Bx)     // mm
        __syncthreads();
        AST128(Ax, Agl + k0, DIN) AST64(Bx, Bgl + k0, DIN)
        __syncthreads();
        COMPUTE_Q(Ah, Bx)     // hl
        COMPUTE_Q(Ax, Bh)     // lh
        __syncthreads();
    }
#undef COMPUTE_Q

    #pragma unroll
    for (int fm = 0; fm < 4; ++fm) {
        const int row = m0 + wr * 64 + fm * 16 + kc * 4;
        #pragma unroll
        for (int fn = 0; fn < 2; ++fn) {
            const int col = n0 + wc * 32 + fn * 16 + r16;
            const float b = bias[col];
            #pragma unroll
            for (int r = 0; r < 4; ++r) {
                const float o = acc[fm][fn][r] + b;
                const unsigned short h = f2bf(o);
                const float rr = o - bf2f(h);
                const unsigned short m = f2bf(rr);
                const unsigned short l = f2bf(rr - bf2f(m));
                const size_t off = (size_t)(row + r) * (HEADS * KDIM) + col;
                qh[off] = h; qm[off] = m; ql[off] = l;
            }
        }
    }
}

// ======= scores (z<8, 6-term) + gate (z==8, 3-term), variant-resident ======
// 128x128 tile, 4 waves, BK=64, T2 swizzle.  LDS 64 KB.  Async staging.
__global__ __launch_bounds__(256)
void mfma_sg(const unsigned short* __restrict__ qh, const unsigned short* __restrict__ qm,
             const unsigned short* __restrict__ ql,
             const unsigned short* __restrict__ kh, const unsigned short* __restrict__ km,
             const unsigned short* __restrict__ kl,
             const unsigned short* __restrict__ xh, const unsigned short* __restrict__ xm,
             const unsigned short* __restrict__ wh, const unsigned short* __restrict__ wm,
             const float* __restrict__ bsw,
             float* __restrict__ s, float* __restrict__ gate)
{
    __shared__ __align__(16) unsigned short Ah[128 * 64];
    __shared__ __align__(16) unsigned short Bh[128 * 64];
    __shared__ __align__(16) unsigned short Ax[128 * 64];
    __shared__ __align__(16) unsigned short Bx[128 * 64];
    const int tid  = threadIdx.x;
    const int wid  = tid >> 6, lane = tid & 63;
    const int r16  = lane & 15, kc = lane >> 4;
    const int wr   = wid >> 1, wc = wid & 1;
    const int z    = blockIdx.z;
    const int bx   = blockIdx.x, by = blockIdx.y;

    const unsigned short *Agh, *Agm, *Agl, *Bgh, *Bgm, *Bgl;
    int K, lda, ldb;
    if (z < 8) {
        const size_t aoff = (size_t)(bx * 128) * (HEADS * KDIM)
                          + (z >> 1) * KDIM + (z & 1) * HALFD;
        const size_t boff = ((size_t)z * NKEYS + by * 128) * HALFD;
        Agh = qh + aoff; Agm = qm + aoff; Agl = ql + aoff;
        Bgh = kh + boff; Bgm = km + boff; Bgl = kl + boff;
        K = HALFD; lda = HEADS * KDIM; ldb = HALFD;
    } else {
        const size_t aoff = (size_t)(bx * 128) * DIN;
        const size_t boff = (size_t)(by * 128) * DIN;
        Agh = xh + aoff; Agm = xm + aoff; Agl = nullptr;
        Bgh = wh + boff; Bgm = wm + boff; Bgl = nullptr;
        K = DIN; lda = DIN; ldb = DIN;
    }

    f32x4 acc[4][4] = {};

#define COMPUTE_SG(bufA, bufB)                                               \
    _Pragma("unroll")                                                        \
    for (int ks = 0; ks < 2; ++ks) {                                         \
        bf16x8 af[4], bf[4];                                                 \
        _Pragma("unroll")                                                    \
        for (int f = 0; f < 4; ++f) {                                        \
            const int am = wr * 64 + f * 16 + r16;                           \
            af[f] = *(const bf16x8*)((const char*)(bufA) +                   \
                ((unsigned)(am * 128 + ks * 64 + kc * 16) ^ ((am & 7) << 4)));\
            const int bn = wc * 64 + f * 16 + r16;                           \
            bf[f] = *(const bf16x8*)((const char*)(bufB) +                   \
                ((unsigned)(bn * 128 + ks * 64 + kc * 16) ^ ((bn & 7) << 4)));\
        }                                                                    \
        _Pragma("unroll")                                                    \
        for (int fm = 0; fm < 4; ++fm)                                       \
            _Pragma("unroll")                                                \
            for (int fn = 0; fn < 4; ++fn)                                   \
                acc[fm][fn] = __builtin_amdgcn_mfma_f32_16x16x32_bf16(       \
                    af[fm], bf[fn], acc[fm][fn], 0, 0, 0);                   \
    }

    for (int k0 = 0; k0 < K; k0 += 64) {
        AST128(Ah, Agh + k0, lda) AST128(Bh, Bgh + k0, ldb)
        AST128(Ax, Agm + k0, lda) AST128(Bx, Bgm + k0, ldb)
        __syncthreads();
        COMPUTE_SG(Ah, Bh)      // hh
        COMPUTE_SG(Ah, Bx)      // hm
        COMPUTE_SG(Ax, Bh)      // mh
        if (z < 8) {
            COMPUTE_SG(Ax, Bx)  // mm
            __syncthreads();
            AST128(Ax, Agl + k0, lda) AST128(Bx, Bgl + k0, ldb)
            __syncthreads();
            COMPUTE_SG(Ah, Bx)  // hl
            COMPUTE_SG(Ax, Bh)  // lh
        }
        __syncthreads();
    }
#undef COMPUTE_SG

    #pragma unroll
    for (int fm = 0; fm < 4; ++fm) {
        const int row = bx * 128 + wr * 64 + fm * 16 + kc * 4;
        #pragma unroll
        for (int fn = 0; fn < 4; ++fn) {
            const int col = by * 128 + wc * 64 + fn * 16 + r16;
            #pragma unroll
            for (int r = 0; r < 4; ++r) {
                float v = acc[fm][fn][r];
                if (z < 8) {
                    s[(size_t)(row + r) * (HEADS * 2 * NKEYS) + z * NKEYS + col] = v;
                } else {
                    v += bsw[col];
                    v = v / (1.f + expf(-v));
                    gate[(size_t)(row + r) * DOUT + col] = v;
                }
            }
        }
    }
}

// ====== topk4 (R11-proven): tau-select [32,64] -> bitonic top-32 -> stage 2
__global__ __launch_bounds__(64)
void topk4(const float* __restrict__ s,
           float* __restrict__ w_out, int* __restrict__ idx_out)
{
    const int nh   = blockIdx.x;
    const int lane = threadIdx.x;
    const int sub  = lane >> 5;
    const int sl   = lane & 31;
    __shared__ unsigned long long pkl[2][64];
    __shared__ float ts[2][KNN];
    __shared__ int   ti[2][KNN];

    const float* sb = s + (size_t)nh * (2 * NKEYS) + sub * NKEYS;
    unsigned u[16];
    #pragma unroll
    for (int i = 0; i < 16; ++i) u[i] = fmap(sb[i * 32 + sl]);

    unsigned lo = 0, hi = 0xFFFFFFFFu, tau = 0;
    bool found = false;
    for (int iter = 0; iter < 30; ++iter) {
        if (__all(found)) break;
        const unsigned mid = lo + ((hi - lo) >> 1);
        int c = 0;
        #pragma unroll
        for (int i = 0; i < 16; ++i) c += (u[i] >= mid) ? 1 : 0;
        #pragma unroll
        for (int off = 1; off <= 16; off <<= 1) c += __shfl_xor(c, off);
        if (!found) {
            if (c >= 32 && c <= 64) { tau = mid; found = true; }
            else if (c > 64) lo = mid + 1;
            else hi = mid - 1;
        }
    }
    if (!found) tau = lo;

    pkl[0][lane] = 0ull;
    pkl[1][lane] = 0ull;
    __syncthreads();
    unsigned msk = 0;
    #pragma unroll
    for (int i = 0; i < 16; ++i) msk |= (u[i] >= tau ? 1u : 0u) << i;
    int mc = __popc(msk);
    int pfx = mc;
    #pragma unroll
    for (int d = 1; d <= 16; d <<= 1) {
        const int t = __shfl_up(pfx, d);
        if (sl >= d) pfx += t;
    }
    int slot = pfx - mc;
    #pragma unroll
    for (int i = 0; i < 16; ++i)
        if ((msk >> i) & 1u) {
            if (slot < 64)
                pkl[sub][slot] = ((unsigned long long)u[i] << 32)
                               | (unsigned)(~((i << 5) | sl));
            ++slot;
        }
    __syncthreads();

    #pragma unroll
    for (int p = 0; p < 2; ++p) {
        unsigned long long v = bitonic64_desc(pkl[p][lane], lane);
        if (lane < KNN) {
            ts[p][lane] = funmap((unsigned)(v >> 32));
            ti[p][lane] = (int)(~(unsigned)v) & (NKEYS - 1);
        }
    }
    __syncthreads();

    float cv[2]; int cc[2];
    #pragma unroll
    for (int t = 0; t < 2; ++t) {
        const int c = t * 64 + lane;
        int ii = -1, jj = 0, off = 0;
        #pragma unroll
        for (int i = 0; i < 32; ++i) {
            const int cnt = 32 / (i + 1);
            const bool in = (c >= off) && (c < off + cnt);
            ii = in ? i : ii;
            jj = in ? c - off : jj;
            off += cnt;
        }
        if (ii >= 0) { cv[t] = ts[0][ii] + ts[1][jj]; cc[t] = ii * 32 + jj; }
        else         { cv[t] = -INFINITY;             cc[t] = 0x7fffffff;  }
    }

    unsigned used2 = 0;
    float mval = 0.f, myval = -INFINITY;
    int mycombo = 0;
    for (int it = 0; it < KNN; ++it) {
        float bv = -INFINITY; int bc = 0x7fffffff;
        #pragma unroll
        for (int t = 0; t < 2; ++t) {
            const bool live = !((used2 >> t) & 1u);
            const bool better = live &&
                (cv[t] > bv || (cv[t] == bv && cc[t] < bc));
            bv = better ? cv[t] : bv;
            bc = better ? cc[t] : bc;
        }
        float m = bv;
        #pragma unroll
        for (int off = 32; off; off >>= 1) m = fmaxf(m, __shfl_xor(m, off));
        const unsigned long long bal = __ballot(bv == m);
        int combo;
        if (__popcll(bal) == 1) {
            combo = __shfl(bc, (int)(__ffsll(bal) - 1));
        } else {
            unsigned cm = (bv == m) ? (unsigned)bc : 0xffffffffu;
            #pragma unroll
            for (int off = 32; off; off >>= 1) cm = min(cm, __shfl_xor(cm, off));
            combo = (int)cm;
        }
        if (it == 0) mval = m;
        if (lane == it) { myval = m; mycombo = combo; }
        #pragma unroll
        for (int t = 0; t < 2; ++t)
            if (cc[t] == combo) used2 |= 1u << t;
    }

    const float ew = (lane < KNN) ? expf(myval - mval) : 0.f;
    float ssum = ew;
    #pragma unroll
    for (int off = 32; off; off >>= 1) ssum += __shfl_xor(ssum, off);
    if (lane < KNN) {
        const int i1 = ti[0][mycombo >> 5];
        const int i2 = ti[1][mycombo & 31];
        w_out[(size_t)nh * KNN + lane] = ew / ssum;
        idx_out[(size_t)nh * KNN + lane] = i1 * NKEYS + i2;
    }
}

// =========== weighted embedding-bag gather + gate -> bf16 hi/lo out0 =======
__global__ __launch_bounds__(256)
void gather_kernel(const float* __restrict__ values,
                   const float* __restrict__ w, const int* __restrict__ idx,
                   const float* __restrict__ gate,
                   unsigned short* __restrict__ o0h, unsigned short* __restrict__ o0l)
{
    const int n = blockIdx.x;
    const int t = threadIdx.x;
    __shared__ float sw[HEADS * KNN];
    __shared__ int   sidx[HEADS * KNN];
    if (t < HEADS * KNN) {
        sw[t]   = w[(size_t)n * HEADS * KNN + t];
        sidx[t] = idx[(size_t)n * HEADS * KNN + t];
    }
    __syncthreads();
    const int d0 = t * 2;
    float2 acc = {0.f, 0.f};
    #pragma unroll 8
    for (int k = 0; k < HEADS * KNN; ++k) {
        const float2 v = *(const float2*)(values + (size_t)sidx[k] * DOUT + d0);
        const float ww = sw[k];
        acc.x = fmaf(ww, v.x, acc.x);
        acc.y = fmaf(ww, v.y, acc.y);
    }
    const float2 g = *(const float2*)(gate + (size_t)n * DOUT + d0);
    const float vx = acc.x * g.x;
    const float vy = acc.y * g.y;
    ushort2 h, l;
    h.x = f2bf(vx); l.x = f2bf(vx - bf2f(h.x));
    h.y = f2bf(vy); l.y = f2bf(vy - bf2f(h.y));
    *(ushort2*)(o0h + (size_t)n * DOUT + d0) = h;
    *(ushort2*)(o0l + (size_t)n * DOUT + d0) = l;
}

// =========== final projection: out = out0 @ Wv^T + bv (3-term MFMA) ========
__global__ __launch_bounds__(256)
void mfma_out(const unsigned short* __restrict__ o0h, const unsigned short* __restrict__ o0l,
              const unsigned short* __restrict__ vh, const unsigned short* __restrict__ vm,
              const float* __restrict__ bv, float* __restrict__ out)
{
    __shared__ __align__(16) unsigned short Al[64 * 64];
    __shared__ __align__(16) unsigned short Bl[64 * 64];
    const int tid = threadIdx.x;
    const int wid = tid >> 6, lane = tid & 63;
    const int r16 = lane & 15, kc = lane >> 4;
    const int wr = wid >> 1, wc = wid & 1;
    const int m0 = blockIdx.x * 64, n0 = blockIdx.y * 64;
    const int srow = tid >> 2;
    const int skb  = (tid & 3) << 4;
    const unsigned swzw = (unsigned)((srow & 7) << 4);

    f32x4 acc[2][2] = {};
    #pragma unroll
    for (int term = 0; term < 3; ++term) {
        const unsigned short* Ag = ((term == 2) ? o0l : o0h) + (size_t)(m0 + srow) * DOUT + skb;
        const unsigned short* Bg = ((term == 1) ? vm : vh) + (size_t)(n0 + srow) * DOUT + skb;
        for (int k0 = 0; k0 < DOUT; k0 += 64) {
            __syncthreads();
            const uint4 va0 = *(const uint4*)(Ag + k0);
            const uint4 va1 = *(const uint4*)(Ag + k0 + 8);
            const uint4 vb0 = *(const uint4*)(Bg + k0);
            const uint4 vb1 = *(const uint4*)(Bg + k0 + 8);
            const unsigned b0 = (unsigned)(srow * 128 + skb * 2) ^ swzw;
            const unsigned b1 = (unsigned)(srow * 128 + skb * 2 + 16) ^ swzw;
            *(uint4*)((char*)Al + b0) = va0; *(uint4*)((char*)Al + b1) = va1;
            *(uint4*)((char*)Bl + b0) = vb0; *(uint4*)((char*)Bl + b1) = vb1;
            __syncthreads();
            #pragma unroll
            for (int ks = 0; ks < 2; ++ks) {
                bf16x8 af[2], bf[2];
                #pragma unroll
                for (int f = 0; f < 2; ++f) {
                    const int am = wr * 32 + f * 16 + r16;
                    af[f] = *(const bf16x8*)((const char*)Al +
                        ((unsigned)(am * 128 + ks * 64 + kc * 16) ^ ((am & 7) << 4)));
                    const int bn = wc * 32 + f * 16 + r16;
                    bf[f] = *(const bf16x8*)((const char*)Bl +
                        ((unsigned)(bn * 128 + ks * 64 + kc * 16) ^ ((bn & 7) << 4)));
                }
                #pragma unroll
                for (int fm = 0; fm < 2; ++fm)
                    #pragma unroll
                    for (int fn = 0; fn < 2; ++fn)
                        acc[fm][fn] = __builtin_amdgcn_mfma_f32_16x16x32_bf16(
                            af[fm], bf[fn], acc[fm][fn], 0, 0, 0);
            }
        }
    }

    #pragma unroll
    for (int fm = 0; fm < 2; ++fm) {
        const int row = m0 + wr * 32 + fm * 16 + kc * 4;
        #pragma unroll
        for (int fn = 0; fn < 2; ++fn) {
            const int col = n0 + wc * 32 + fn * 16 + r16;
            const float b = bv[col];
            #pragma unroll
            for (int r = 0; r < 4; ++r)
                out[(size_t)(row + r) * DOUT + col] = acc[fm][fn][r] + b;
        }
    }
}

}  // namespace

extern "C" void kernel_launch(void* const* d_in, const int* in_sizes, int n_in,
                              void* d_out, int out_size, void* d_ws, size_t ws_size,
                              hipStream_t stream)
{
    const float* x      = (const float*)d_in[0];
    const float* Wq     = (const float*)d_in[1];
    const float* bq     = (const float*)d_in[2];
    const float* keys   = (const float*)d_in[3];
    const float* values = (const float*)d_in[4];
    const float* Wsw    = (const float*)d_in[5];
    const float* bsw    = (const float*)d_in[6];
    const float* Wv     = (const float*)d_in[7];
    const float* bv     = (const float*)d_in[8];
    float* out = (float*)d_out;

    // workspace layout (bf16 arrays, all 16B-aligned by construction)
    unsigned short* qh  = (unsigned short*)d_ws;                      // 8MB
    unsigned short* qm  = qh + (size_t)NROWS * HEADS * KDIM;          // 8MB
    unsigned short* ql  = qm + (size_t)NROWS * HEADS * KDIM;          // 8MB
    float*          s   = (float*)(ql + (size_t)NROWS * HEADS * KDIM); // 32MB
    unsigned short* xh  = (unsigned short*)(s + (size_t)NROWS * HEADS * 2 * NKEYS);
    unsigned short* xm  = xh + (size_t)NROWS * DIN;
    unsigned short* xl  = xm + (size_t)NROWS * DIN;
    unsigned short* wh  = xl + (size_t)NROWS * DIN;
    unsigned short* wm  = wh + (size_t)DOUT * DIN;
    unsigned short* kh  = wm + (size_t)DOUT * DIN;
    unsigned short* km  = kh + (size_t)8 * NKEYS * HALFD;
    unsigned short* kl  = km + (size_t)8 * NKEYS * HALFD;
    unsigned short* vh  = kl + (size_t)8 * NKEYS * HALFD;
    unsigned short* vm  = vh + (size_t)DOUT * DOUT;
    unsigned short* qwh = vm + (size_t)DOUT * DOUT;
    unsigned short* qwm = qwh + (size_t)HEADS * KDIM * DIN;
    unsigned short* qwl = qwm + (size_t)HEADS * KDIM * DIN;
    float*          wsc = (float*)(qwl + (size_t)HEADS * KDIM * DIN);
    int*            idxb = (int*)(wsc + (size_t)NROWS * HEADS * KNN);
    float*          gate = (float*)(idxb + (size_t)NROWS * HEADS * KNN);
    unsigned short* o0h  = (unsigned short*)(gate + (size_t)NROWS * DOUT);
    unsigned short* o0l  = o0h + (size_t)NROWS * DOUT;

    const dim3 blk(256);

    // 1) splits: x/keys/Wq 3-way, Wsw/Wv 2-way
    split6<<<dim3(1024, 1, 5), blk, 0, stream>>>(
        x, Wsw, keys, Wv, Wq,
        xh, xm, xl, wh, wm, kh, km, kl, vh, vm, qwh, qwm, qwl);

    // 2) q = x @ Wq^T + bq  (6-term, variant-resident, async stage)
    mfma_q<<<dim3(16, 32), blk, 0, stream>>>(
        xh, xm, xl, qwh, qwm, qwl, bq, qh, qm, ql);

    // 3) scores (z<8, 6-term) + gate (z==8, 3-term), async stage
    mfma_sg<<<dim3(16, 4, 9), blk, 0, stream>>>(
        qh, qm, ql, kh, km, kl, xh, xm, wh, wm, bsw, s, gate);

    // 4) tau-select -> bitonic exact top-32 -> stage 2 + softmax
    topk4<<<dim3(NROWS * HEADS), dim3(64), 0, stream>>>(s, wsc, idxb);

    // 5) out0 = (sum_k w*values[idx]) * gate  -> bf16 hi/lo
    gather_kernel<<<dim3(NROWS), blk, 0, stream>>>(
        values, wsc, idxb, gate, o0h, o0l);

    // 6) out = out0 @ Wv^T + bv  (3-term split MFMA)
    mfma_out<<<dim3(32, 8), blk, 0, stream>>>(o0h, o0l, vh, vm, bv, out);
}

// Round 15
// 226.230 us; speedup vs baseline: 1.3829x; 1.0786x over previous
//
#include <hip/hip_runtime.h>
#include <math.h>

namespace {

constexpr int NROWS = 2048;   // B*T
constexpr int DIN   = 512;
constexpr int DOUT  = 512;
constexpr int HEADS = 4;
constexpr int KDIM  = 512;
constexpr int HALFD = 256;
constexpr int NKEYS = 512;
constexpr int KNN   = 32;

typedef short bf16x8 __attribute__((ext_vector_type(8)));
typedef float f32x4  __attribute__((ext_vector_type(4)));
typedef const __attribute__((address_space(1))) void gvoid_t;
typedef __attribute__((address_space(3))) void lvoid_t;

__device__ inline unsigned short f2bf(float f) {   // round-to-nearest-even
    unsigned u = __float_as_uint(f);
    unsigned r = u + 0x7FFFu + ((u >> 16) & 1u);
    return (unsigned short)(r >> 16);
}
__device__ inline float bf2f(unsigned short h) {
    return __uint_as_float((unsigned)h << 16);
}
__device__ inline unsigned fmap(float f) {
    unsigned u = __float_as_uint(f);
    return (u & 0x80000000u) ? ~u : (u | 0x80000000u);
}
__device__ inline float funmap(unsigned m) {
    unsigned u = (m & 0x80000000u) ? (m & 0x7FFFFFFFu) : ~m;
    return __uint_as_float(u);
}
__device__ inline unsigned long long shflxor64(unsigned long long x, int m) {
    unsigned lo = (unsigned)x, hi = (unsigned)(x >> 32);
    lo = __shfl_xor(lo, m);
    hi = __shfl_xor(hi, m);
    return ((unsigned long long)hi << 32) | lo;
}
// full 64-lane bitonic sort, descending by u64 key; lane l ends with rank-l
__device__ inline unsigned long long bitonic64_desc(unsigned long long v, int lane) {
    #pragma unroll
    for (int k = 2; k <= 64; k <<= 1) {
        #pragma unroll
        for (int j = k >> 1; j > 0; j >>= 1) {
            const unsigned long long o = shflxor64(v, j);
            const bool keepMax = (((lane & j) == 0) == ((lane & k) == 0));
            const bool oGreater = o > v;
            v = (keepMax == oGreater) ? o : v;
        }
    }
    return v;
}

// ====== splits: x 3-way (z0), Wsw 2-way (z1), keys 3-way (z2),
//                Wv 2-way (z3), Wq 3-way (z4)
__global__ __launch_bounds__(256)
void split6(const float* __restrict__ x, const float* __restrict__ wsw,
            const float* __restrict__ keys, const float* __restrict__ wv,
            const float* __restrict__ wq,
            unsigned short* __restrict__ xh, unsigned short* __restrict__ xm,
            unsigned short* __restrict__ xl,
            unsigned short* __restrict__ wh, unsigned short* __restrict__ wm,
            unsigned short* __restrict__ kh, unsigned short* __restrict__ km,
            unsigned short* __restrict__ kl,
            unsigned short* __restrict__ vh, unsigned short* __restrict__ vm,
            unsigned short* __restrict__ qwh, unsigned short* __restrict__ qwm,
            unsigned short* __restrict__ qwl)
{
    const int z = blockIdx.z;
    const int i = (blockIdx.x * 256 + threadIdx.x) * 4;
    const bool three = (z == 0) || (z == 2) || (z == 4);
    const float* src = (z == 0) ? x : (z == 1) ? wsw : (z == 2) ? keys
                     : (z == 3) ? wv : wq;
    unsigned short* ph = (z == 0) ? xh : (z == 1) ? wh : (z == 2) ? kh
                       : (z == 3) ? vh : qwh;
    unsigned short* pm = (z == 0) ? xm : (z == 1) ? wm : (z == 2) ? km
                       : (z == 3) ? vm : qwm;
    unsigned short* pl = (z == 0) ? xl : (z == 2) ? kl : qwl;
    const int n = (z == 1 || z == 3) ? 262144 : 1048576;
    if (i >= n) return;
    const float4 v = *(const float4*)(src + i);
    ushort4 oh, om, ol;
    float r;
    oh.x = f2bf(v.x); r = v.x - bf2f(oh.x); om.x = f2bf(r); ol.x = f2bf(r - bf2f(om.x));
    oh.y = f2bf(v.y); r = v.y - bf2f(oh.y); om.y = f2bf(r); ol.y = f2bf(r - bf2f(om.y));
    oh.z = f2bf(v.z); r = v.z - bf2f(oh.z); om.z = f2bf(r); ol.z = f2bf(r - bf2f(om.z));
    oh.w = f2bf(v.w); r = v.w - bf2f(oh.w); om.w = f2bf(r); ol.w = f2bf(r - bf2f(om.w));
    *(ushort4*)(ph + i) = oh;
    *(ushort4*)(pm + i) = om;
    if (three) *(ushort4*)(pl + i) = ol;
}

// ---- async stage: linear LDS dest + inverse-swizzled global source --------
// LDS chunk c (16B) of row r holds global chunk c ^ (r&7)  [== R13 layout].
#define AST128(buf, G, ldg)                                                  \
    _Pragma("unroll")                                                        \
    for (int ii_ = 0; ii_ < 4; ++ii_) {                                      \
        const int r0_ = (wid * 4 + ii_) * 8;                                 \
        const int row_ = r0_ + (lane >> 3);                                  \
        const int cs_ = (lane & 7) ^ (row_ & 7);                             \
        __builtin_amdgcn_global_load_lds(                                    \
            (gvoid_t*)((G) + (size_t)row_ * (ldg) + cs_ * 8),                \
            (lvoid_t*)((char*)(buf) + r0_ * 128), 16, 0, 0);                 \
    }
#define AST64(buf, G, ldg)                                                   \
    _Pragma("unroll")                                                        \
    for (int ii_ = 0; ii_ < 2; ++ii_) {                                      \
        const int r0_ = (wid * 2 + ii_) * 8;                                 \
        const int row_ = r0_ + (lane >> 3);                                  \
        const int cs_ = (lane & 7) ^ (row_ & 7);                             \
        __builtin_amdgcn_global_load_lds(                                    \
            (gvoid_t*)((G) + (size_t)row_ * (ldg) + cs_ * 8),                \
            (lvoid_t*)((char*)(buf) + r0_ * 128), 16, 0, 0);                 \
    }

// ===== q = x @ Wq^T + bq, 6-term triple-split MFMA, 6-panel resident =======
// 128x64 tile, grid (16,32)=512 blocks (2/CU).  LDS 72 KB.  2 barriers/k0.
__global__ __launch_bounds__(256)
void mfma_q(const unsigned short* __restrict__ xh, const unsigned short* __restrict__ xm,
            const unsigned short* __restrict__ xl,
            const unsigned short* __restrict__ WH, const unsigned short* __restrict__ WM,
            const unsigned short* __restrict__ WL,
            const float* __restrict__ bias,
            unsigned short* __restrict__ qh, unsigned short* __restrict__ qm,
            unsigned short* __restrict__ ql)
{
    __shared__ __align__(16) unsigned short Ah[128 * 64];
    __shared__ __align__(16) unsigned short Am[128 * 64];
    __shared__ __align__(16) unsigned short Al[128 * 64];
    __shared__ __align__(16) unsigned short Bh[64 * 64];
    __shared__ __align__(16) unsigned short Bm[64 * 64];
    __shared__ __align__(16) unsigned short Bl[64 * 64];
    const int tid = threadIdx.x;
    const int wid = tid >> 6, lane = tid & 63;
    const int r16 = lane & 15, kc = lane >> 4;
    const int wr = wid >> 1, wc = wid & 1;
    const int m0 = blockIdx.x * 128, n0 = blockIdx.y * 64;

    const unsigned short* Agh = xh + (size_t)m0 * DIN;
    const unsigned short* Agm = xm + (size_t)m0 * DIN;
    const unsigned short* Agl = xl + (size_t)m0 * DIN;
    const unsigned short* Bgh = WH + (size_t)n0 * DIN;
    const unsigned short* Bgm = WM + (size_t)n0 * DIN;
    const unsigned short* Bgl = WL + (size_t)n0 * DIN;

    f32x4 acc[4][2] = {};

#define COMPUTE_Q(bufA, bufB)                                                \
    _Pragma("unroll")                                                        \
    for (int ks = 0; ks < 2; ++ks) {                                         \
        bf16x8 af[4], bfr[2];                                                \
        _Pragma("unroll")                                                    \
        for (int f = 0; f < 4; ++f) {                                        \
            const int am = wr * 64 + f * 16 + r16;                           \
            af[f] = *(const bf16x8*)((const char*)(bufA) +                   \
                ((unsigned)(am * 128 + ks * 64 + kc * 16) ^ ((am & 7) << 4)));\
        }                                                                    \
        _Pragma("unroll")                                                    \
        for (int f = 0; f < 2; ++f) {                                        \
            const int bn = wc * 32 + f * 16 + r16;                           \
            bfr[f] = *(const bf16x8*)((const char*)(bufB) +                  \
                ((unsigned)(bn * 128 + ks * 64 + kc * 16) ^ ((bn & 7) << 4)));\
        }                                                                    \
        _Pragma("unroll")                                                    \
        for (int fm = 0; fm < 4; ++fm)                                       \
            _Pragma("unroll")                                                \
            for (int fn = 0; fn < 2; ++fn)                                   \
                acc[fm][fn] = __builtin_amdgcn_mfma_f32_16x16x32_bf16(       \
                    af[fm], bfr[fn], acc[fm][fn], 0, 0, 0);                  \
    }

    for (int k0 = 0; k0 < DIN; k0 += 64) {
        AST128(Ah, Agh + k0, DIN) AST128(Am, Agm + k0, DIN) AST128(Al, Agl + k0, DIN)
        AST64(Bh, Bgh + k0, DIN)  AST64(Bm, Bgm + k0, DIN)  AST64(Bl, Bgl + k0, DIN)
        __syncthreads();
        COMPUTE_Q(Ah, Bh)     // hh
        COMPUTE_Q(Ah, Bm)     // hm
        COMPUTE_Q(Am, Bh)     // mh
        COMPUTE_Q(Am, Bm)     // mm
        COMPUTE_Q(Ah, Bl)     // hl
        COMPUTE_Q(Al, Bh)     // lh
        __syncthreads();
    }
#undef COMPUTE_Q

    #pragma unroll
    for (int fm = 0; fm < 4; ++fm) {
        const int row = m0 + wr * 64 + fm * 16 + kc * 4;
        #pragma unroll
        for (int fn = 0; fn < 2; ++fn) {
            const int col = n0 + wc * 32 + fn * 16 + r16;
            const float b = bias[col];
            #pragma unroll
            for (int r = 0; r < 4; ++r) {
                const float o = acc[fm][fn][r] + b;
                const unsigned short h = f2bf(o);
                const float rr = o - bf2f(h);
                const unsigned short m = f2bf(rr);
                const unsigned short l = f2bf(rr - bf2f(m));
                const size_t off = (size_t)(row + r) * (HEADS * KDIM) + col;
                qh[off] = h; qm[off] = m; ql[off] = l;
            }
        }
    }
}

// ======= gate (z==0, 3-term) + scores (z>=1, 6-term), variant-resident =====
// 128x128 tile, 4 waves, BK=64, T2 swizzle.  LDS 64 KB.  Async staging.
// Gate blocks are ~25% longer -> dispatched FIRST (z==0) to avoid tail.
__global__ __launch_bounds__(256)
void mfma_sg(const unsigned short* __restrict__ qh, const unsigned short* __restrict__ qm,
             const unsigned short* __restrict__ ql,
             const unsigned short* __restrict__ kh, const unsigned short* __restrict__ km,
             const unsigned short* __restrict__ kl,
             const unsigned short* __restrict__ xh, const unsigned short* __restrict__ xm,
             const unsigned short* __restrict__ wh, const unsigned short* __restrict__ wm,
             const float* __restrict__ bsw,
             float* __restrict__ s, float* __restrict__ gate)
{
    __shared__ __align__(16) unsigned short Ah[128 * 64];
    __shared__ __align__(16) unsigned short Bh[128 * 64];
    __shared__ __align__(16) unsigned short Ax[128 * 64];
    __shared__ __align__(16) unsigned short Bx[128 * 64];
    const int tid  = threadIdx.x;
    const int wid  = tid >> 6, lane = tid & 63;
    const int r16  = lane & 15, kc = lane >> 4;
    const int wr   = wid >> 1, wc = wid & 1;
    const int z    = blockIdx.z;          // 0 = gate, 1..8 = score z-1
    const int bx   = blockIdx.x, by = blockIdx.y;

    const unsigned short *Agh, *Agm, *Agl, *Bgh, *Bgm, *Bgl;
    int K, lda, ldb;
    if (z >= 1) {
        const int zz = z - 1;
        const size_t aoff = (size_t)(bx * 128) * (HEADS * KDIM)
                          + (zz >> 1) * KDIM + (zz & 1) * HALFD;
        const size_t boff = ((size_t)zz * NKEYS + by * 128) * HALFD;
        Agh = qh + aoff; Agm = qm + aoff; Agl = ql + aoff;
        Bgh = kh + boff; Bgm = km + boff; Bgl = kl + boff;
        K = HALFD; lda = HEADS * KDIM; ldb = HALFD;
    } else {
        const size_t aoff = (size_t)(bx * 128) * DIN;
        const size_t boff = (size_t)(by * 128) * DIN;
        Agh = xh + aoff; Agm = xm + aoff; Agl = nullptr;
        Bgh = wh + boff; Bgm = wm + boff; Bgl = nullptr;
        K = DIN; lda = DIN; ldb = DIN;
    }

    f32x4 acc[4][4] = {};

#define COMPUTE_SG(bufA, bufB)                                               \
    _Pragma("unroll")                                                        \
    for (int ks = 0; ks < 2; ++ks) {                                         \
        bf16x8 af[4], bf[4];                                                 \
        _Pragma("unroll")                                                    \
        for (int f = 0; f < 4; ++f) {                                        \
            const int am = wr * 64 + f * 16 + r16;                           \
            af[f] = *(const bf16x8*)((const char*)(bufA) +                   \
                ((unsigned)(am * 128 + ks * 64 + kc * 16) ^ ((am & 7) << 4)));\
            const int bn = wc * 64 + f * 16 + r16;                           \
            bf[f] = *(const bf16x8*)((const char*)(bufB) +                   \
                ((unsigned)(bn * 128 + ks * 64 + kc * 16) ^ ((bn & 7) << 4)));\
        }                                                                    \
        _Pragma("unroll")                                                    \
        for (int fm = 0; fm < 4; ++fm)                                       \
            _Pragma("unroll")                                                \
            for (int fn = 0; fn < 4; ++fn)                                   \
                acc[fm][fn] = __builtin_amdgcn_mfma_f32_16x16x32_bf16(       \
                    af[fm], bf[fn], acc[fm][fn], 0, 0, 0);                   \
    }

    for (int k0 = 0; k0 < K; k0 += 64) {
        AST128(Ah, Agh + k0, lda) AST128(Bh, Bgh + k0, ldb)
        AST128(Ax, Agm + k0, lda) AST128(Bx, Bgm + k0, ldb)
        __syncthreads();
        COMPUTE_SG(Ah, Bh)      // hh
        COMPUTE_SG(Ah, Bx)      // hm
        COMPUTE_SG(Ax, Bh)      // mh
        if (z >= 1) {
            COMPUTE_SG(Ax, Bx)  // mm
            __syncthreads();
            AST128(Ax, Agl + k0, lda) AST128(Bx, Bgl + k0, ldb)
            __syncthreads();
            COMPUTE_SG(Ah, Bx)  // hl
            COMPUTE_SG(Ax, Bh)  // lh
        }
        __syncthreads();
    }
#undef COMPUTE_SG

    #pragma unroll
    for (int fm = 0; fm < 4; ++fm) {
        const int row = bx * 128 + wr * 64 + fm * 16 + kc * 4;
        #pragma unroll
        for (int fn = 0; fn < 4; ++fn) {
            const int col = by * 128 + wc * 64 + fn * 16 + r16;
            #pragma unroll
            for (int r = 0; r < 4; ++r) {
                float v = acc[fm][fn][r];
                if (z >= 1) {
                    s[(size_t)(row + r) * (HEADS * 2 * NKEYS) + (z - 1) * NKEYS + col] = v;
                } else {
                    v += bsw[col];
                    v = v / (1.f + expf(-v));
                    gate[(size_t)(row + r) * DOUT + col] = v;
                }
            }
        }
    }
}

// ====== topk4 (R11-proven): tau-select [32,64] -> bitonic top-32 -> stage 2
__global__ __launch_bounds__(64)
void topk4(const float* __restrict__ s,
           float* __restrict__ w_out, int* __restrict__ idx_out)
{
    const int nh   = blockIdx.x;
    const int lane = threadIdx.x;
    const int sub  = lane >> 5;
    const int sl   = lane & 31;
    __shared__ unsigned long long pkl[2][64];
    __shared__ float ts[2][KNN];
    __shared__ int   ti[2][KNN];

    const float* sb = s + (size_t)nh * (2 * NKEYS) + sub * NKEYS;
    unsigned u[16];
    #pragma unroll
    for (int i = 0; i < 16; ++i) u[i] = fmap(sb[i * 32 + sl]);

    unsigned lo = 0, hi = 0xFFFFFFFFu, tau = 0;
    bool found = false;
    for (int iter = 0; iter < 30; ++iter) {
        if (__all(found)) break;
        const unsigned mid = lo + ((hi - lo) >> 1);
        int c = 0;
        #pragma unroll
        for (int i = 0; i < 16; ++i) c += (u[i] >= mid) ? 1 : 0;
        #pragma unroll
        for (int off = 1; off <= 16; off <<= 1) c += __shfl_xor(c, off);
        if (!found) {
            if (c >= 32 && c <= 64) { tau = mid; found = true; }
            else if (c > 64) lo = mid + 1;
            else hi = mid - 1;
        }
    }
    if (!found) tau = lo;

    pkl[0][lane] = 0ull;
    pkl[1][lane] = 0ull;
    __syncthreads();
    unsigned msk = 0;
    #pragma unroll
    for (int i = 0; i < 16; ++i) msk |= (u[i] >= tau ? 1u : 0u) << i;
    int mc = __popc(msk);
    int pfx = mc;
    #pragma unroll
    for (int d = 1; d <= 16; d <<= 1) {
        const int t = __shfl_up(pfx, d);
        if (sl >= d) pfx += t;
    }
    int slot = pfx - mc;
    #pragma unroll
    for (int i = 0; i < 16; ++i)
        if ((msk >> i) & 1u) {
            if (slot < 64)
                pkl[sub][slot] = ((unsigned long long)u[i] << 32)
                               | (unsigned)(~((i << 5) | sl));
            ++slot;
        }
    __syncthreads();

    #pragma unroll
    for (int p = 0; p < 2; ++p) {
        unsigned long long v = bitonic64_desc(pkl[p][lane], lane);
        if (lane < KNN) {
            ts[p][lane] = funmap((unsigned)(v >> 32));
            ti[p][lane] = (int)(~(unsigned)v) & (NKEYS - 1);
        }
    }
    __syncthreads();

    float cv[2]; int cc[2];
    #pragma unroll
    for (int t = 0; t < 2; ++t) {
        const int c = t * 64 + lane;
        int ii = -1, jj = 0, off = 0;
        #pragma unroll
        for (int i = 0; i < 32; ++i) {
            const int cnt = 32 / (i + 1);
            const bool in = (c >= off) && (c < off + cnt);
            ii = in ? i : ii;
            jj = in ? c - off : jj;
            off += cnt;
        }
        if (ii >= 0) { cv[t] = ts[0][ii] + ts[1][jj]; cc[t] = ii * 32 + jj; }
        else         { cv[t] = -INFINITY;             cc[t] = 0x7fffffff;  }
    }

    unsigned used2 = 0;
    float mval = 0.f, myval = -INFINITY;
    int mycombo = 0;
    for (int it = 0; it < KNN; ++it) {
        float bv = -INFINITY; int bc = 0x7fffffff;
        #pragma unroll
        for (int t = 0; t < 2; ++t) {
            const bool live = !((used2 >> t) & 1u);
            const bool better = live &&
                (cv[t] > bv || (cv[t] == bv && cc[t] < bc));
            bv = better ? cv[t] : bv;
            bc = better ? cc[t] : bc;
        }
        float m = bv;
        #pragma unroll
        for (int off = 32; off; off >>= 1) m = fmaxf(m, __shfl_xor(m, off));
        const unsigned long long bal = __ballot(bv == m);
        int combo;
        if (__popcll(bal) == 1) {
            combo = __shfl(bc, (int)(__ffsll(bal) - 1));
        } else {
            unsigned cm = (bv == m) ? (unsigned)bc : 0xffffffffu;
            #pragma unroll
            for (int off = 32; off; off >>= 1) cm = min(cm, __shfl_xor(cm, off));
            combo = (int)cm;
        }
        if (it == 0) mval = m;
        if (lane == it) { myval = m; mycombo = combo; }
        #pragma unroll
        for (int t = 0; t < 2; ++t)
            if (cc[t] == combo) used2 |= 1u << t;
    }

    const float ew = (lane < KNN) ? expf(myval - mval) : 0.f;
    float ssum = ew;
    #pragma unroll
    for (int off = 32; off; off >>= 1) ssum += __shfl_xor(ssum, off);
    if (lane < KNN) {
        const int i1 = ti[0][mycombo >> 5];
        const int i2 = ti[1][mycombo & 31];
        w_out[(size_t)nh * KNN + lane] = ew / ssum;
        idx_out[(size_t)nh * KNN + lane] = i1 * NKEYS + i2;
    }
}

// =========== weighted embedding-bag gather + gate -> bf16 hi/lo out0 =======
__global__ __launch_bounds__(256)
void gather_kernel(const float* __restrict__ values,
                   const float* __restrict__ w, const int* __restrict__ idx,
                   const float* __restrict__ gate,
                   unsigned short* __restrict__ o0h, unsigned short* __restrict__ o0l)
{
    const int n = blockIdx.x;
    const int t = threadIdx.x;
    __shared__ float sw[HEADS * KNN];
    __shared__ int   sidx[HEADS * KNN];
    if (t < HEADS * KNN) {
        sw[t]   = w[(size_t)n * HEADS * KNN + t];
        sidx[t] = idx[(size_t)n * HEADS * KNN + t];
    }
    __syncthreads();
    const int d0 = t * 2;
    float2 acc = {0.f, 0.f};
    #pragma unroll 8
    for (int k = 0; k < HEADS * KNN; ++k) {
        const float2 v = *(const float2*)(values + (size_t)sidx[k] * DOUT + d0);
        const float ww = sw[k];
        acc.x = fmaf(ww, v.x, acc.x);
        acc.y = fmaf(ww, v.y, acc.y);
    }
    const float2 g = *(const float2*)(gate + (size_t)n * DOUT + d0);
    const float vx = acc.x * g.x;
    const float vy = acc.y * g.y;
    ushort2 h, l;
    h.x = f2bf(vx); l.x = f2bf(vx - bf2f(h.x));
    h.y = f2bf(vy); l.y = f2bf(vy - bf2f(h.y));
    *(ushort2*)(o0h + (size_t)n * DOUT + d0) = h;
    *(ushort2*)(o0l + (size_t)n * DOUT + d0) = l;
}

// =========== final projection: out = out0 @ Wv^T + bv (3-term MFMA) ========
__global__ __launch_bounds__(256)
void mfma_out(const unsigned short* __restrict__ o0h, const unsigned short* __restrict__ o0l,
              const unsigned short* __restrict__ vh, const unsigned short* __restrict__ vm,
              const float* __restrict__ bv, float* __restrict__ out)
{
    __shared__ __align__(16) unsigned short Al[64 * 64];
    __shared__ __align__(16) unsigned short Bl[64 * 64];
    const int tid = threadIdx.x;
    const int wid = tid >> 6, lane = tid & 63;
    const int r16 = lane & 15, kc = lane >> 4;
    const int wr = wid >> 1, wc = wid & 1;
    const int m0 = blockIdx.x * 64, n0 = blockIdx.y * 64;
    const int srow = tid >> 2;
    const int skb  = (tid & 3) << 4;
    const unsigned swzw = (unsigned)((srow & 7) << 4);

    f32x4 acc[2][2] = {};
    #pragma unroll
    for (int term = 0; term < 3; ++term) {
        const unsigned short* Ag = ((term == 2) ? o0l : o0h) + (size_t)(m0 + srow) * DOUT + skb;
        const unsigned short* Bg = ((term == 1) ? vm : vh) + (size_t)(n0 + srow) * DOUT + skb;
        for (int k0 = 0; k0 < DOUT; k0 += 64) {
            __syncthreads();
            const uint4 va0 = *(const uint4*)(Ag + k0);
            const uint4 va1 = *(const uint4*)(Ag + k0 + 8);
            const uint4 vb0 = *(const uint4*)(Bg + k0);
            const uint4 vb1 = *(const uint4*)(Bg + k0 + 8);
            const unsigned b0 = (unsigned)(srow * 128 + skb * 2) ^ swzw;
            const unsigned b1 = (unsigned)(srow * 128 + skb * 2 + 16) ^ swzw;
            *(uint4*)((char*)Al + b0) = va0; *(uint4*)((char*)Al + b1) = va1;
            *(uint4*)((char*)Bl + b0) = vb0; *(uint4*)((char*)Bl + b1) = vb1;
            __syncthreads();
            #pragma unroll
            for (int ks = 0; ks < 2; ++ks) {
                bf16x8 af[2], bf[2];
                #pragma unroll
                for (int f = 0; f < 2; ++f) {
                    const int am = wr * 32 + f * 16 + r16;
                    af[f] = *(const bf16x8*)((const char*)Al +
                        ((unsigned)(am * 128 + ks * 64 + kc * 16) ^ ((am & 7) << 4)));
                    const int bn = wc * 32 + f * 16 + r16;
                    bf[f] = *(const bf16x8*)((const char*)Bl +
                        ((unsigned)(bn * 128 + ks * 64 + kc * 16) ^ ((bn & 7) << 4)));
                }
                #pragma unroll
                for (int fm = 0; fm < 2; ++fm)
                    #pragma unroll
                    for (int fn = 0; fn < 2; ++fn)
                        acc[fm][fn] = __builtin_amdgcn_mfma_f32_16x16x32_bf16(
                            af[fm], bf[fn], acc[fm][fn], 0, 0, 0);
            }
        }
    }

    #pragma unroll
    for (int fm = 0; fm < 2; ++fm) {
        const int row = m0 + wr * 32 + fm * 16 + kc * 4;
        #pragma unroll
        for (int fn = 0; fn < 2; ++fn) {
            const int col = n0 + wc * 32 + fn * 16 + r16;
            const float b = bv[col];
            #pragma unroll
            for (int r = 0; r < 4; ++r)
                out[(size_t)(row + r) * DOUT + col] = acc[fm][fn][r] + b;
        }
    }
}

}  // namespace

extern "C" void kernel_launch(void* const* d_in, const int* in_sizes, int n_in,
                              void* d_out, int out_size, void* d_ws, size_t ws_size,
                              hipStream_t stream)
{
    const float* x      = (const float*)d_in[0];
    const float* Wq     = (const float*)d_in[1];
    const float* bq     = (const float*)d_in[2];
    const float* keys   = (const float*)d_in[3];
    const float* values = (const float*)d_in[4];
    const float* Wsw    = (const float*)d_in[5];
    const float* bsw    = (const float*)d_in[6];
    const float* Wv     = (const float*)d_in[7];
    const float* bv     = (const float*)d_in[8];
    float* out = (float*)d_out;

    // workspace layout (bf16 arrays, all 16B-aligned by construction)
    unsigned short* qh  = (unsigned short*)d_ws;                      // 8MB
    unsigned short* qm  = qh + (size_t)NROWS * HEADS * KDIM;          // 8MB
    unsigned short* ql  = qm + (size_t)NROWS * HEADS * KDIM;          // 8MB
    float*          s   = (float*)(ql + (size_t)NROWS * HEADS * KDIM); // 32MB
    unsigned short* xh  = (unsigned short*)(s + (size_t)NROWS * HEADS * 2 * NKEYS);
    unsigned short* xm  = xh + (size_t)NROWS * DIN;
    unsigned short* xl  = xm + (size_t)NROWS * DIN;
    unsigned short* wh  = xl + (size_t)NROWS * DIN;
    unsigned short* wm  = wh + (size_t)DOUT * DIN;
    unsigned short* kh  = wm + (size_t)DOUT * DIN;
    unsigned short* km  = kh + (size_t)8 * NKEYS * HALFD;
    unsigned short* kl  = km + (size_t)8 * NKEYS * HALFD;
    unsigned short* vh  = kl + (size_t)8 * NKEYS * HALFD;
    unsigned short* vm  = vh + (size_t)DOUT * DOUT;
    unsigned short* qwh = vm + (size_t)DOUT * DOUT;
    unsigned short* qwm = qwh + (size_t)HEADS * KDIM * DIN;
    unsigned short* qwl = qwm + (size_t)HEADS * KDIM * DIN;
    float*          wsc = (float*)(qwl + (size_t)HEADS * KDIM * DIN);
    int*            idxb = (int*)(wsc + (size_t)NROWS * HEADS * KNN);
    float*          gate = (float*)(idxb + (size_t)NROWS * HEADS * KNN);
    unsigned short* o0h  = (unsigned short*)(gate + (size_t)NROWS * DOUT);
    unsigned short* o0l  = o0h + (size_t)NROWS * DOUT;

    const dim3 blk(256);

    // 1) splits: x/keys/Wq 3-way, Wsw/Wv 2-way
    split6<<<dim3(1024, 1, 5), blk, 0, stream>>>(
        x, Wsw, keys, Wv, Wq,
        xh, xm, xl, wh, wm, kh, km, kl, vh, vm, qwh, qwm, qwl);

    // 2) q = x @ Wq^T + bq  (6-term, 6-panel resident, async stage)
    mfma_q<<<dim3(16, 32), blk, 0, stream>>>(
        xh, xm, xl, qwh, qwm, qwl, bq, qh, qm, ql);

    // 3) gate (z==0, long blocks first) + scores (z=1..8), async stage
    mfma_sg<<<dim3(16, 4, 9), blk, 0, stream>>>(
        qh, qm, ql, kh, km, kl, xh, xm, wh, wm, bsw, s, gate);

    // 4) tau-select -> bitonic exact top-32 -> stage 2 + softmax
    topk4<<<dim3(NROWS * HEADS), dim3(64), 0, stream>>>(s, wsc, idxb);

    // 5) out0 = (sum_k w*values[idx]) * gate  -> bf16 hi/lo
    gather_kernel<<<dim3(NROWS), blk, 0, stream>>>(
        values, wsc, idxb, gate, o0h, o0l);

    // 6) out = out0 @ Wv^T + bv  (3-term split MFMA)
    mfma_out<<<dim3(32, 8), blk, 0, stream>>>(o0h, o0l, vh, vm, bv, out);
}

// Round 16
// 202.577 us; speedup vs baseline: 1.5443x; 1.1168x over previous
//
#include <hip/hip_runtime.h>
#include <math.h>

namespace {

constexpr int NROWS = 2048;   // B*T
constexpr int DIN   = 512;
constexpr int DOUT  = 512;
constexpr int HEADS = 4;
constexpr int KDIM  = 512;
constexpr int HALFD = 256;
constexpr int NKEYS = 512;
constexpr int KNN   = 32;

typedef short bf16x8 __attribute__((ext_vector_type(8)));
typedef float f32x4  __attribute__((ext_vector_type(4)));
typedef const __attribute__((address_space(1))) void gvoid_t;
typedef __attribute__((address_space(3))) void lvoid_t;

__device__ inline unsigned short f2bf(float f) {   // round-to-nearest-even
    unsigned u = __float_as_uint(f);
    unsigned r = u + 0x7FFFu + ((u >> 16) & 1u);
    return (unsigned short)(r >> 16);
}
__device__ inline float bf2f(unsigned short h) {
    return __uint_as_float((unsigned)h << 16);
}
__device__ inline unsigned fmap(float f) {
    unsigned u = __float_as_uint(f);
    return (u & 0x80000000u) ? ~u : (u | 0x80000000u);
}
__device__ inline float funmap(unsigned m) {
    unsigned u = (m & 0x80000000u) ? (m & 0x7FFFFFFFu) : ~m;
    return __uint_as_float(u);
}
__device__ inline unsigned long long shflxor64(unsigned long long x, int m) {
    unsigned lo = (unsigned)x, hi = (unsigned)(x >> 32);
    lo = __shfl_xor(lo, m);
    hi = __shfl_xor(hi, m);
    return ((unsigned long long)hi << 32) | lo;
}
// full 64-lane bitonic sort, descending by u64 key; lane l ends with rank-l
__device__ inline unsigned long long bitonic64_desc(unsigned long long v, int lane) {
    #pragma unroll
    for (int k = 2; k <= 64; k <<= 1) {
        #pragma unroll
        for (int j = k >> 1; j > 0; j >>= 1) {
            const unsigned long long o = shflxor64(v, j);
            const bool keepMax = (((lane & j) == 0) == ((lane & k) == 0));
            const bool oGreater = o > v;
            v = (keepMax == oGreater) ? o : v;
        }
    }
    return v;
}

// ====== splits: x 3-way (z0), Wsw 2-way (z1), keys 3-way (z2),
//                Wv 2-way (z3), Wq 3-way (z4)
__global__ __launch_bounds__(256)
void split6(const float* __restrict__ x, const float* __restrict__ wsw,
            const float* __restrict__ keys, const float* __restrict__ wv,
            const float* __restrict__ wq,
            unsigned short* __restrict__ xh, unsigned short* __restrict__ xm,
            unsigned short* __restrict__ xl,
            unsigned short* __restrict__ wh, unsigned short* __restrict__ wm,
            unsigned short* __restrict__ kh, unsigned short* __restrict__ km,
            unsigned short* __restrict__ kl,
            unsigned short* __restrict__ vh, unsigned short* __restrict__ vm,
            unsigned short* __restrict__ qwh, unsigned short* __restrict__ qwm,
            unsigned short* __restrict__ qwl)
{
    const int z = blockIdx.z;
    const int i = (blockIdx.x * 256 + threadIdx.x) * 4;
    const bool three = (z == 0) || (z == 2) || (z == 4);
    const float* src = (z == 0) ? x : (z == 1) ? wsw : (z == 2) ? keys
                     : (z == 3) ? wv : wq;
    unsigned short* ph = (z == 0) ? xh : (z == 1) ? wh : (z == 2) ? kh
                       : (z == 3) ? vh : qwh;
    unsigned short* pm = (z == 0) ? xm : (z == 1) ? wm : (z == 2) ? km
                       : (z == 3) ? vm : qwm;
    unsigned short* pl = (z == 0) ? xl : (z == 2) ? kl : qwl;
    const int n = (z == 1 || z == 3) ? 262144 : 1048576;
    if (i >= n) return;
    const float4 v = *(const float4*)(src + i);
    ushort4 oh, om, ol;
    float r;
    oh.x = f2bf(v.x); r = v.x - bf2f(oh.x); om.x = f2bf(r); ol.x = f2bf(r - bf2f(om.x));
    oh.y = f2bf(v.y); r = v.y - bf2f(oh.y); om.y = f2bf(r); ol.y = f2bf(r - bf2f(om.y));
    oh.z = f2bf(v.z); r = v.z - bf2f(oh.z); om.z = f2bf(r); ol.z = f2bf(r - bf2f(om.z));
    oh.w = f2bf(v.w); r = v.w - bf2f(oh.w); om.w = f2bf(r); ol.w = f2bf(r - bf2f(om.w));
    *(ushort4*)(ph + i) = oh;
    *(ushort4*)(pm + i) = om;
    if (three) *(ushort4*)(pl + i) = ol;
}

// ---- async stage: linear LDS dest + inverse-swizzled global source --------
// LDS chunk c (16B) of row r holds global chunk c ^ (r&7)  [== R13 layout].
#define AST128(buf, G, ldg)                                                  \
    _Pragma("unroll")                                                        \
    for (int ii_ = 0; ii_ < 4; ++ii_) {                                      \
        const int r0_ = (wid * 4 + ii_) * 8;                                 \
        const int row_ = r0_ + (lane >> 3);                                  \
        const int cs_ = (lane & 7) ^ (row_ & 7);                             \
        __builtin_amdgcn_global_load_lds(                                    \
            (gvoid_t*)((G) + (size_t)row_ * (ldg) + cs_ * 8),                \
            (lvoid_t*)((char*)(buf) + r0_ * 128), 16, 0, 0);                 \
    }
#define AST64(buf, G, ldg)                                                   \
    _Pragma("unroll")                                                        \
    for (int ii_ = 0; ii_ < 2; ++ii_) {                                      \
        const int r0_ = (wid * 2 + ii_) * 8;                                 \
        const int row_ = r0_ + (lane >> 3);                                  \
        const int cs_ = (lane & 7) ^ (row_ & 7);                             \
        __builtin_amdgcn_global_load_lds(                                    \
            (gvoid_t*)((G) + (size_t)row_ * (ldg) + cs_ * 8),                \
            (lvoid_t*)((char*)(buf) + r0_ * 128), 16, 0, 0);                 \
    }

// ===== q = x @ Wq^T + bq, 6-term triple-split MFMA, 6-panel resident =======
// 128x64 tile, grid (16,32)=512 blocks (2/CU).  LDS 72 KB.  2 barriers/k0.
__global__ __launch_bounds__(256)
void mfma_q(const unsigned short* __restrict__ xh, const unsigned short* __restrict__ xm,
            const unsigned short* __restrict__ xl,
            const unsigned short* __restrict__ WH, const unsigned short* __restrict__ WM,
            const unsigned short* __restrict__ WL,
            const float* __restrict__ bias,
            unsigned short* __restrict__ qh, unsigned short* __restrict__ qm,
            unsigned short* __restrict__ ql)
{
    __shared__ __align__(16) unsigned short Ah[128 * 64];
    __shared__ __align__(16) unsigned short Am[128 * 64];
    __shared__ __align__(16) unsigned short Al[128 * 64];
    __shared__ __align__(16) unsigned short Bh[64 * 64];
    __shared__ __align__(16) unsigned short Bm[64 * 64];
    __shared__ __align__(16) unsigned short Bl[64 * 64];
    const int tid = threadIdx.x;
    const int wid = tid >> 6, lane = tid & 63;
    const int r16 = lane & 15, kc = lane >> 4;
    const int wr = wid >> 1, wc = wid & 1;
    const int m0 = blockIdx.x * 128, n0 = blockIdx.y * 64;

    const unsigned short* Agh = xh + (size_t)m0 * DIN;
    const unsigned short* Agm = xm + (size_t)m0 * DIN;
    const unsigned short* Agl = xl + (size_t)m0 * DIN;
    const unsigned short* Bgh = WH + (size_t)n0 * DIN;
    const unsigned short* Bgm = WM + (size_t)n0 * DIN;
    const unsigned short* Bgl = WL + (size_t)n0 * DIN;

    f32x4 acc[4][2] = {};

#define COMPUTE_Q(bufA, bufB)                                                \
    _Pragma("unroll")                                                        \
    for (int ks = 0; ks < 2; ++ks) {                                         \
        bf16x8 af[4], bfr[2];                                                \
        _Pragma("unroll")                                                    \
        for (int f = 0; f < 4; ++f) {                                        \
            const int am = wr * 64 + f * 16 + r16;                           \
            af[f] = *(const bf16x8*)((const char*)(bufA) +                   \
                ((unsigned)(am * 128 + ks * 64 + kc * 16) ^ ((am & 7) << 4)));\
        }                                                                    \
        _Pragma("unroll")                                                    \
        for (int f = 0; f < 2; ++f) {                                        \
            const int bn = wc * 32 + f * 16 + r16;                           \
            bfr[f] = *(const bf16x8*)((const char*)(bufB) +                  \
                ((unsigned)(bn * 128 + ks * 64 + kc * 16) ^ ((bn & 7) << 4)));\
        }                                                                    \
        _Pragma("unroll")                                                    \
        for (int fm = 0; fm < 4; ++fm)                                       \
            _Pragma("unroll")                                                \
            for (int fn = 0; fn < 2; ++fn)                                   \
                acc[fm][fn] = __builtin_amdgcn_mfma_f32_16x16x32_bf16(       \
                    af[fm], bfr[fn], acc[fm][fn], 0, 0, 0);                  \
    }

    for (int k0 = 0; k0 < DIN; k0 += 64) {
        AST128(Ah, Agh + k0, DIN) AST128(Am, Agm + k0, DIN) AST128(Al, Agl + k0, DIN)
        AST64(Bh, Bgh + k0, DIN)  AST64(Bm, Bgm + k0, DIN)  AST64(Bl, Bgl + k0, DIN)
        __syncthreads();
        COMPUTE_Q(Ah, Bh)     // hh
        COMPUTE_Q(Ah, Bm)     // hm
        COMPUTE_Q(Am, Bh)     // mh
        COMPUTE_Q(Am, Bm)     // mm
        COMPUTE_Q(Ah, Bl)     // hl
        COMPUTE_Q(Al, Bh)     // lh
        __syncthreads();
    }
#undef COMPUTE_Q

    #pragma unroll
    for (int fm = 0; fm < 4; ++fm) {
        const int row = m0 + wr * 64 + fm * 16 + kc * 4;
        #pragma unroll
        for (int fn = 0; fn < 2; ++fn) {
            const int col = n0 + wc * 32 + fn * 16 + r16;
            const float b = bias[col];
            #pragma unroll
            for (int r = 0; r < 4; ++r) {
                const float o = acc[fm][fn][r] + b;
                const unsigned short h = f2bf(o);
                const float rr = o - bf2f(h);
                const unsigned short m = f2bf(rr);
                const unsigned short l = f2bf(rr - bf2f(m));
                const size_t off = (size_t)(row + r) * (HEADS * KDIM) + col;
                qh[off] = h; qm[off] = m; ql[off] = l;
            }
        }
    }
}

// ======= gate (z==0, 3-term) + scores (z>=1, 6-term), variant-resident =====
// 128x128 tile, 4 waves, BK=64, T2 swizzle.  LDS 64 KB.  Async staging.
__global__ __launch_bounds__(256)
void mfma_sg(const unsigned short* __restrict__ qh, const unsigned short* __restrict__ qm,
             const unsigned short* __restrict__ ql,
             const unsigned short* __restrict__ kh, const unsigned short* __restrict__ km,
             const unsigned short* __restrict__ kl,
             const unsigned short* __restrict__ xh, const unsigned short* __restrict__ xm,
             const unsigned short* __restrict__ wh, const unsigned short* __restrict__ wm,
             const float* __restrict__ bsw,
             float* __restrict__ s, float* __restrict__ gate)
{
    __shared__ __align__(16) unsigned short Ah[128 * 64];
    __shared__ __align__(16) unsigned short Bh[128 * 64];
    __shared__ __align__(16) unsigned short Ax[128 * 64];
    __shared__ __align__(16) unsigned short Bx[128 * 64];
    const int tid  = threadIdx.x;
    const int wid  = tid >> 6, lane = tid & 63;
    const int r16  = lane & 15, kc = lane >> 4;
    const int wr   = wid >> 1, wc = wid & 1;
    const int z    = blockIdx.z;          // 0 = gate, 1..8 = score z-1
    const int bx   = blockIdx.x, by = blockIdx.y;

    const unsigned short *Agh, *Agm, *Agl, *Bgh, *Bgm, *Bgl;
    int K, lda, ldb;
    if (z >= 1) {
        const int zz = z - 1;
        const size_t aoff = (size_t)(bx * 128) * (HEADS * KDIM)
                          + (zz >> 1) * KDIM + (zz & 1) * HALFD;
        const size_t boff = ((size_t)zz * NKEYS + by * 128) * HALFD;
        Agh = qh + aoff; Agm = qm + aoff; Agl = ql + aoff;
        Bgh = kh + boff; Bgm = km + boff; Bgl = kl + boff;
        K = HALFD; lda = HEADS * KDIM; ldb = HALFD;
    } else {
        const size_t aoff = (size_t)(bx * 128) * DIN;
        const size_t boff = (size_t)(by * 128) * DIN;
        Agh = xh + aoff; Agm = xm + aoff; Agl = nullptr;
        Bgh = wh + boff; Bgm = wm + boff; Bgl = nullptr;
        K = DIN; lda = DIN; ldb = DIN;
    }

    f32x4 acc[4][4] = {};

#define COMPUTE_SG(bufA, bufB)                                               \
    _Pragma("unroll")                                                        \
    for (int ks = 0; ks < 2; ++ks) {                                         \
        bf16x8 af[4], bf[4];                                                 \
        _Pragma("unroll")                                                    \
        for (int f = 0; f < 4; ++f) {                                        \
            const int am = wr * 64 + f * 16 + r16;                           \
            af[f] = *(const bf16x8*)((const char*)(bufA) +                   \
                ((unsigned)(am * 128 + ks * 64 + kc * 16) ^ ((am & 7) << 4)));\
            const int bn = wc * 64 + f * 16 + r16;                           \
            bf[f] = *(const bf16x8*)((const char*)(bufB) +                   \
                ((unsigned)(bn * 128 + ks * 64 + kc * 16) ^ ((bn & 7) << 4)));\
        }                                                                    \
        _Pragma("unroll")                                                    \
        for (int fm = 0; fm < 4; ++fm)                                       \
            _Pragma("unroll")                                                \
            for (int fn = 0; fn < 4; ++fn)                                   \
                acc[fm][fn] = __builtin_amdgcn_mfma_f32_16x16x32_bf16(       \
                    af[fm], bf[fn], acc[fm][fn], 0, 0, 0);                   \
    }

    for (int k0 = 0; k0 < K; k0 += 64) {
        AST128(Ah, Agh + k0, lda) AST128(Bh, Bgh + k0, ldb)
        AST128(Ax, Agm + k0, lda) AST128(Bx, Bgm + k0, ldb)
        __syncthreads();
        COMPUTE_SG(Ah, Bh)      // hh
        COMPUTE_SG(Ah, Bx)      // hm
        COMPUTE_SG(Ax, Bh)      // mh
        if (z >= 1) {
            COMPUTE_SG(Ax, Bx)  // mm
            __syncthreads();
            AST128(Ax, Agl + k0, lda) AST128(Bx, Bgl + k0, ldb)
            __syncthreads();
            COMPUTE_SG(Ah, Bx)  // hl
            COMPUTE_SG(Ax, Bh)  // lh
        }
        __syncthreads();
    }
#undef COMPUTE_SG

    #pragma unroll
    for (int fm = 0; fm < 4; ++fm) {
        const int row = bx * 128 + wr * 64 + fm * 16 + kc * 4;
        #pragma unroll
        for (int fn = 0; fn < 4; ++fn) {
            const int col = by * 128 + wc * 64 + fn * 16 + r16;
            #pragma unroll
            for (int r = 0; r < 4; ++r) {
                float v = acc[fm][fn][r];
                if (z >= 1) {
                    s[(size_t)(row + r) * (HEADS * 2 * NKEYS) + (z - 1) * NKEYS + col] = v;
                } else {
                    v += bsw[col];
                    v = v / (1.f + expf(-v));
                    gate[(size_t)(row + r) * DOUT + col] = v;
                }
            }
        }
    }
}

// ====== fused: per-row topk (wave h = head h, R11-proven logic) + gather ===
// Block = row n, 256 threads (4 waves).  All __syncthreads uniform.
__global__ __launch_bounds__(256)
void topk_gather(const float* __restrict__ s, const float* __restrict__ values,
                 const float* __restrict__ gate,
                 unsigned short* __restrict__ o0h, unsigned short* __restrict__ o0l)
{
    const int n    = blockIdx.x;
    const int h    = threadIdx.x >> 6;   // wave = head
    const int lane = threadIdx.x & 63;
    const int sub  = lane >> 5;
    const int sl   = lane & 31;
    __shared__ unsigned long long pkl[HEADS][2][64];
    __shared__ float ts[HEADS][2][KNN];
    __shared__ int   ti[HEADS][2][KNN];
    __shared__ float sw[HEADS * KNN];
    __shared__ int   sidx[HEADS * KNN];

    const int nh = n * HEADS + h;
    const float* sb = s + (size_t)nh * (2 * NKEYS) + sub * NKEYS;
    unsigned u[16];
    #pragma unroll
    for (int i = 0; i < 16; ++i) u[i] = fmap(sb[i * 32 + sl]);

    // tau-bisect: count(u >= tau) in [32,64] per half
    unsigned lo = 0, hi = 0xFFFFFFFFu, tau = 0;
    bool found = false;
    for (int iter = 0; iter < 30; ++iter) {
        if (__all(found)) break;
        const unsigned mid = lo + ((hi - lo) >> 1);
        int c = 0;
        #pragma unroll
        for (int i = 0; i < 16; ++i) c += (u[i] >= mid) ? 1 : 0;
        #pragma unroll
        for (int off = 1; off <= 16; off <<= 1) c += __shfl_xor(c, off);
        if (!found) {
            if (c >= 32 && c <= 64) { tau = mid; found = true; }
            else if (c > 64) lo = mid + 1;
            else hi = mid - 1;
        }
    }
    if (!found) tau = lo;

    pkl[h][0][lane] = 0ull;
    pkl[h][1][lane] = 0ull;
    __syncthreads();
    unsigned msk = 0;
    #pragma unroll
    for (int i = 0; i < 16; ++i) msk |= (u[i] >= tau ? 1u : 0u) << i;
    int mc = __popc(msk);
    int pfx = mc;
    #pragma unroll
    for (int d = 1; d <= 16; d <<= 1) {
        const int t = __shfl_up(pfx, d);
        if (sl >= d) pfx += t;
    }
    int slot = pfx - mc;
    #pragma unroll
    for (int i = 0; i < 16; ++i)
        if ((msk >> i) & 1u) {
            if (slot < 64)
                pkl[h][sub][slot] = ((unsigned long long)u[i] << 32)
                                  | (unsigned)(~((i << 5) | sl));
            ++slot;
        }
    __syncthreads();

    // bitonic-64 descending per half; lane<32 holds exact top-32
    #pragma unroll
    for (int p = 0; p < 2; ++p) {
        unsigned long long v = bitonic64_desc(pkl[h][p][lane], lane);
        if (lane < KNN) {
            ts[h][p][lane] = funmap((unsigned)(v >> 32));
            ti[h][p][lane] = (int)(~(unsigned)v) & (NKEYS - 1);
        }
    }
    __syncthreads();

    // stage 2: top-32 of the 119 pruned cartesian sums
    float cv[2]; int cc[2];
    #pragma unroll
    for (int t = 0; t < 2; ++t) {
        const int c = t * 64 + lane;
        int ii = -1, jj = 0, off = 0;
        #pragma unroll
        for (int i = 0; i < 32; ++i) {
            const int cnt = 32 / (i + 1);
            const bool in = (c >= off) && (c < off + cnt);
            ii = in ? i : ii;
            jj = in ? c - off : jj;
            off += cnt;
        }
        if (ii >= 0) { cv[t] = ts[h][0][ii] + ts[h][1][jj]; cc[t] = ii * 32 + jj; }
        else         { cv[t] = -INFINITY;                   cc[t] = 0x7fffffff;  }
    }

    unsigned used2 = 0;
    float mval = 0.f, myval = -INFINITY;
    int mycombo = 0;
    for (int it = 0; it < KNN; ++it) {
        float bv = -INFINITY; int bc = 0x7fffffff;
        #pragma unroll
        for (int t = 0; t < 2; ++t) {
            const bool live = !((used2 >> t) & 1u);
            const bool better = live &&
                (cv[t] > bv || (cv[t] == bv && cc[t] < bc));
            bv = better ? cv[t] : bv;
            bc = better ? cc[t] : bc;
        }
        float m = bv;
        #pragma unroll
        for (int off = 32; off; off >>= 1) m = fmaxf(m, __shfl_xor(m, off));
        const unsigned long long bal = __ballot(bv == m);
        int combo;
        if (__popcll(bal) == 1) {
            combo = __shfl(bc, (int)(__ffsll(bal) - 1));
        } else {
            unsigned cm = (bv == m) ? (unsigned)bc : 0xffffffffu;
            #pragma unroll
            for (int off = 32; off; off >>= 1) cm = min(cm, __shfl_xor(cm, off));
            combo = (int)cm;
        }
        if (it == 0) mval = m;
        if (lane == it) { myval = m; mycombo = combo; }
        #pragma unroll
        for (int t = 0; t < 2; ++t)
            if (cc[t] == combo) used2 |= 1u << t;
    }

    const float ew = (lane < KNN) ? expf(myval - mval) : 0.f;
    float ssum = ew;
    #pragma unroll
    for (int off = 32; off; off >>= 1) ssum += __shfl_xor(ssum, off);
    if (lane < KNN) {
        const int i1 = ti[h][0][mycombo >> 5];
        const int i2 = ti[h][1][mycombo & 31];
        sw[h * KNN + lane]   = ew / ssum;
        sidx[h * KNN + lane] = i1 * NKEYS + i2;
    }
    __syncthreads();

    // ---- gather: thread t owns columns 2t, 2t+1 (identical to R15 body) ----
    const int t = threadIdx.x;
    const int d0 = t * 2;
    float2 acc = {0.f, 0.f};
    #pragma unroll 8
    for (int k = 0; k < HEADS * KNN; ++k) {
        const float2 v = *(const float2*)(values + (size_t)sidx[k] * DOUT + d0);
        const float ww = sw[k];
        acc.x = fmaf(ww, v.x, acc.x);
        acc.y = fmaf(ww, v.y, acc.y);
    }
    const float2 g = *(const float2*)(gate + (size_t)n * DOUT + d0);
    const float vx = acc.x * g.x;
    const float vy = acc.y * g.y;
    ushort2 hh, ll;
    hh.x = f2bf(vx); ll.x = f2bf(vx - bf2f(hh.x));
    hh.y = f2bf(vy); ll.y = f2bf(vy - bf2f(hh.y));
    *(ushort2*)(o0h + (size_t)n * DOUT + d0) = hh;
    *(ushort2*)(o0l + (size_t)n * DOUT + d0) = ll;
}

// =========== final projection: out = out0 @ Wv^T + bv (3-term MFMA) ========
__global__ __launch_bounds__(256)
void mfma_out(const unsigned short* __restrict__ o0h, const unsigned short* __restrict__ o0l,
              const unsigned short* __restrict__ vh, const unsigned short* __restrict__ vm,
              const float* __restrict__ bv, float* __restrict__ out)
{
    __shared__ __align__(16) unsigned short Al[64 * 64];
    __shared__ __align__(16) unsigned short Bl[64 * 64];
    const int tid = threadIdx.x;
    const int wid = tid >> 6, lane = tid & 63;
    const int r16 = lane & 15, kc = lane >> 4;
    const int wr = wid >> 1, wc = wid & 1;
    const int m0 = blockIdx.x * 64, n0 = blockIdx.y * 64;
    const int srow = tid >> 2;
    const int skb  = (tid & 3) << 4;
    const unsigned swzw = (unsigned)((srow & 7) << 4);

    f32x4 acc[2][2] = {};
    #pragma unroll
    for (int term = 0; term < 3; ++term) {
        const unsigned short* Ag = ((term == 2) ? o0l : o0h) + (size_t)(m0 + srow) * DOUT + skb;
        const unsigned short* Bg = ((term == 1) ? vm : vh) + (size_t)(n0 + srow) * DOUT + skb;
        for (int k0 = 0; k0 < DOUT; k0 += 64) {
            __syncthreads();
            const uint4 va0 = *(const uint4*)(Ag + k0);
            const uint4 va1 = *(const uint4*)(Ag + k0 + 8);
            const uint4 vb0 = *(const uint4*)(Bg + k0);
            const uint4 vb1 = *(const uint4*)(Bg + k0 + 8);
            const unsigned b0 = (unsigned)(srow * 128 + skb * 2) ^ swzw;
            const unsigned b1 = (unsigned)(srow * 128 + skb * 2 + 16) ^ swzw;
            *(uint4*)((char*)Al + b0) = va0; *(uint4*)((char*)Al + b1) = va1;
            *(uint4*)((char*)Bl + b0) = vb0; *(uint4*)((char*)Bl + b1) = vb1;
            __syncthreads();
            #pragma unroll
            for (int ks = 0; ks < 2; ++ks) {
                bf16x8 af[2], bf[2];
                #pragma unroll
                for (int f = 0; f < 2; ++f) {
                    const int am = wr * 32 + f * 16 + r16;
                    af[f] = *(const bf16x8*)((const char*)Al +
                        ((unsigned)(am * 128 + ks * 64 + kc * 16) ^ ((am & 7) << 4)));
                    const int bn = wc * 32 + f * 16 + r16;
                    bf[f] = *(const bf16x8*)((const char*)Bl +
                        ((unsigned)(bn * 128 + ks * 64 + kc * 16) ^ ((bn & 7) << 4)));
                }
                #pragma unroll
                for (int fm = 0; fm < 2; ++fm)
                    #pragma unroll
                    for (int fn = 0; fn < 2; ++fn)
                        acc[fm][fn] = __builtin_amdgcn_mfma_f32_16x16x32_bf16(
                            af[fm], bf[fn], acc[fm][fn], 0, 0, 0);
            }
        }
    }

    #pragma unroll
    for (int fm = 0; fm < 2; ++fm) {
        const int row = m0 + wr * 32 + fm * 16 + kc * 4;
        #pragma unroll
        for (int fn = 0; fn < 2; ++fn) {
            const int col = n0 + wc * 32 + fn * 16 + r16;
            const float b = bv[col];
            #pragma unroll
            for (int r = 0; r < 4; ++r)
                out[(size_t)(row + r) * DOUT + col] = acc[fm][fn][r] + b;
        }
    }
}

}  // namespace

extern "C" void kernel_launch(void* const* d_in, const int* in_sizes, int n_in,
                              void* d_out, int out_size, void* d_ws, size_t ws_size,
                              hipStream_t stream)
{
    const float* x      = (const float*)d_in[0];
    const float* Wq     = (const float*)d_in[1];
    const float* bq     = (const float*)d_in[2];
    const float* keys   = (const float*)d_in[3];
    const float* values = (const float*)d_in[4];
    const float* Wsw    = (const float*)d_in[5];
    const float* bsw    = (const float*)d_in[6];
    const float* Wv     = (const float*)d_in[7];
    const float* bv     = (const float*)d_in[8];
    float* out = (float*)d_out;

    // workspace layout (bf16 arrays, all 16B-aligned by construction)
    unsigned short* qh  = (unsigned short*)d_ws;                      // 8MB
    unsigned short* qm  = qh + (size_t)NROWS * HEADS * KDIM;          // 8MB
    unsigned short* ql  = qm + (size_t)NROWS * HEADS * KDIM;          // 8MB
    float*          s   = (float*)(ql + (size_t)NROWS * HEADS * KDIM); // 32MB
    unsigned short* xh  = (unsigned short*)(s + (size_t)NROWS * HEADS * 2 * NKEYS);
    unsigned short* xm  = xh + (size_t)NROWS * DIN;
    unsigned short* xl  = xm + (size_t)NROWS * DIN;
    unsigned short* wh  = xl + (size_t)NROWS * DIN;
    unsigned short* wm  = wh + (size_t)DOUT * DIN;
    unsigned short* kh  = wm + (size_t)DOUT * DIN;
    unsigned short* km  = kh + (size_t)8 * NKEYS * HALFD;
    unsigned short* kl  = km + (size_t)8 * NKEYS * HALFD;
    unsigned short* vh  = kl + (size_t)8 * NKEYS * HALFD;
    unsigned short* vm  = vh + (size_t)DOUT * DOUT;
    unsigned short* qwh = vm + (size_t)DOUT * DOUT;
    unsigned short* qwm = qwh + (size_t)HEADS * KDIM * DIN;
    unsigned short* qwl = qwm + (size_t)HEADS * KDIM * DIN;
    unsigned short* o0h = qwl + (size_t)HEADS * KDIM * DIN;
    unsigned short* o0l = o0h + (size_t)NROWS * DOUT;
    float*          gate = (float*)(o0l + (size_t)NROWS * DOUT);

    const dim3 blk(256);

    // 1) splits: x/keys/Wq 3-way, Wsw/Wv 2-way
    split6<<<dim3(1024, 1, 5), blk, 0, stream>>>(
        x, Wsw, keys, Wv, Wq,
        xh, xm, xl, wh, wm, kh, km, kl, vh, vm, qwh, qwm, qwl);

    // 2) q = x @ Wq^T + bq  (6-term, 6-panel resident, async stage)
    mfma_q<<<dim3(16, 32), blk, 0, stream>>>(
        xh, xm, xl, qwh, qwm, qwl, bq, qh, qm, ql);

    // 3) gate (z==0, long blocks first) + scores (z=1..8), async stage
    mfma_sg<<<dim3(16, 4, 9), blk, 0, stream>>>(
        qh, qm, ql, kh, km, kl, xh, xm, wh, wm, bsw, s, gate);

    // 4) fused per-row topk (wave per head) + gather -> bf16 hi/lo out0
    topk_gather<<<dim3(NROWS), blk, 0, stream>>>(
        s, values, gate, o0h, o0l);

    // 5) out = out0 @ Wv^T + bv  (3-term split MFMA)
    mfma_out<<<dim3(32, 8), blk, 0, stream>>>(o0h, o0l, vh, vm, bv, out);
}